// Round 1
// baseline (845.364 us; speedup 1.0000x reference)
//
#include <hip/hip_runtime.h>
#include <hip/hip_bf16.h>
#include <cstdint>
#include <cstddef>

namespace {
constexpr int B  = 8;
constexpr int S  = 768;
constexpr int V  = 384;
constexpr int A  = 384;
constexpr int H  = 8;
constexpr int D  = 64;
constexpr int HD = 512;
constexpr float SCALE = 0.125f;       // d^-0.5, d=64
constexpr float BBC   = 0.6f;
constexpr float NEGV  = -1000000000.0f;
constexpr size_t N_QH = (size_t)B * H * S * D;   // 3145728
}

// ---------------- GEMM: Y = X @ W + bias  (M=6144, N=512, K=512) ----------------
// XHEAD: read X from head layout (B,H,S,D) with row=(b,s), col=(h,dd)
// YHEAD: store Y to head layout
template <int XHEAD, int YHEAD>
__global__ __launch_bounds__(256) void gemm512(const float* __restrict__ X,
                                               const float* __restrict__ W,
                                               const float* __restrict__ bias,
                                               float* __restrict__ Y) {
  __shared__ float As[16][68];
  __shared__ float Bs[16][64];
  const int m0 = blockIdx.x * 64;
  const int n0 = blockIdx.y * 64;
  const int t  = threadIdx.x;
  const int tx = t & 15, ty = t >> 4;
  float acc[4][4] = {};
  for (int k0 = 0; k0 < 512; k0 += 16) {
#pragma unroll
    for (int u = 0; u < 4; ++u) {
      int idx = t + u * 256;
      int kk = idx & 15, mm = idx >> 4;
      int r = m0 + mm, k = k0 + kk;
      size_t xaddr;
      if (XHEAD) {
        int bb = r / S, s = r - bb * S;
        xaddr = ((size_t)(bb * H + (k >> 6)) * S + s) * D + (k & 63);
      } else {
        xaddr = (size_t)r * 512 + k;
      }
      As[kk][mm] = X[xaddr];
    }
#pragma unroll
    for (int u = 0; u < 4; ++u) {
      int idx = t + u * 256;
      int nn = idx & 63, kk = idx >> 6;
      Bs[kk][nn] = W[(size_t)(k0 + kk) * 512 + n0 + nn];
    }
    __syncthreads();
#pragma unroll
    for (int kk = 0; kk < 16; ++kk) {
      float4 a4 = *(float4*)&As[kk][ty * 4];
      float4 b4 = *(float4*)&Bs[kk][tx * 4];
      float a[4] = {a4.x, a4.y, a4.z, a4.w};
      float bb[4] = {b4.x, b4.y, b4.z, b4.w};
#pragma unroll
      for (int i = 0; i < 4; ++i)
#pragma unroll
        for (int j = 0; j < 4; ++j) acc[i][j] += a[i] * bb[j];
    }
    __syncthreads();
  }
  const int c0 = n0 + tx * 4;
  float4 bi = *(const float4*)&bias[c0];
#pragma unroll
  for (int i = 0; i < 4; ++i) {
    int r = m0 + ty * 4 + i;
    float4 o;
    o.x = acc[i][0] + bi.x;
    o.y = acc[i][1] + bi.y;
    o.z = acc[i][2] + bi.z;
    o.w = acc[i][3] + bi.w;
    if (YHEAD) {
      int bb = r / S, s = r - bb * S;
      *(float4*)&Y[((size_t)(bb * H + (c0 >> 6)) * S + s) * D + (c0 & 63)] = o;
    } else {
      *(float4*)&Y[(size_t)r * 512 + c0] = o;
    }
  }
}

// ---------------- fused attention ----------------
// grid: B*H*(S/16); block: 256 threads; thread t: row i=t>>4 (of 16), col-group c=t&15
__global__ __launch_bounds__(256) void attn_kernel(
    float* __restrict__ qh,                 // (B,H,S,D); ctx written back into it
    const float* __restrict__ kh, const float* __restrict__ vh,
    const float* __restrict__ mask,         // (B,S)
    const float* __restrict__ depth_value,  // (B0,V)
    const float* __restrict__ mean_depth,   // (B,A)
    float* __restrict__ att_score, float* __restrict__ att_map,
    float* __restrict__ md_rows)            // (B,H,A)
{
  __shared__ float xs[16][776];
  __shared__ float qs[16][64];
  __shared__ float Ks[64][68];

  const int RB = S / 16;
  const int blk = blockIdx.x;
  const int rb = blk % RB;
  const int bh = blk / RB;
  const int h = bh & (H - 1);
  const int b = bh / H;
  const int b0 = b >> 2;  // rep = B/B0 = 4
  const int i0 = rb * 16;
  const int t = threadIdx.x;
  const int i = t >> 4;
  const int c = t & 15;
  const int row = i0 + i;

  // load q tile, then pull own row into registers
  *(float4*)&qs[i][c * 4] = *(const float4*)&qh[((size_t)bh * S + row) * D + c * 4];
  __syncthreads();
  float4 qr[16];
#pragma unroll
  for (int u = 0; u < 16; ++u) qr[u] = *(float4*)&qs[i][u * 4];

  // ---- scores: xs[i][j] = scale * dot64(q_i, k_j) ----
  for (int kt = 0; kt < S / 64; ++kt) {
    __syncthreads();
#pragma unroll
    for (int u = 0; u < 4; ++u) {
      int f4 = u * 256 + t;
      int jj = f4 >> 4, uu = f4 & 15;
      *(float4*)&Ks[jj][uu * 4] =
          *(const float4*)&kh[((size_t)bh * S + kt * 64 + jj) * D + uu * 4];
    }
    __syncthreads();
#pragma unroll
    for (int n = 0; n < 4; ++n) {
      int jj = c + 16 * n;
      float sacc = 0.f;
#pragma unroll
      for (int u = 0; u < 16; ++u) {
        float4 kv = *(float4*)&Ks[jj][u * 4];
        sacc += qr[u].x * kv.x + qr[u].y * kv.y + qr[u].z * kv.z + qr[u].w * kv.w;
      }
      xs[i][kt * 64 + jj] = sacc * SCALE;
    }
  }
  __syncthreads();

  const float mrow = mask[(size_t)b * S + row];
  const float* mrowp = &mask[(size_t)b * S];

  // ---- AV softmax + md (audio rows, PRE-bias) ----
  if (i0 >= V) {
    const int a = row - V;
    float mx = NEGV;
#pragma unroll
    for (int n = 0; n < 6; ++n) {
      int j = 4 * c + 64 * n;
      float4 xv = *(float4*)&xs[i][j];
      float4 mj = *(const float4*)&mrowp[j];
      mx = fmaxf(mx, (mrow * mj.x > 0.f) ? xv.x : NEGV);
      mx = fmaxf(mx, (mrow * mj.y > 0.f) ? xv.y : NEGV);
      mx = fmaxf(mx, (mrow * mj.z > 0.f) ? xv.z : NEGV);
      mx = fmaxf(mx, (mrow * mj.w > 0.f) ? xv.w : NEGV);
    }
#pragma unroll
    for (int o = 8; o >= 1; o >>= 1) mx = fmaxf(mx, __shfl_xor(mx, o, 16));
    float se = 0.f, sem = 0.f, semd = 0.f;
#pragma unroll
    for (int n = 0; n < 6; ++n) {
      int j = 4 * c + 64 * n;
      float4 xv = *(float4*)&xs[i][j];
      float4 mj = *(const float4*)&mrowp[j];
      float4 dv = *(const float4*)&depth_value[(size_t)b0 * V + j];
      {
        float m4 = mrow * mj.x; float val = m4 > 0.f ? xv.x : NEGV;
        float e = __expf(val - mx); se += e; sem += e * m4; semd += e * m4 * dv.x;
      }
      {
        float m4 = mrow * mj.y; float val = m4 > 0.f ? xv.y : NEGV;
        float e = __expf(val - mx); se += e; sem += e * m4; semd += e * m4 * dv.y;
      }
      {
        float m4 = mrow * mj.z; float val = m4 > 0.f ? xv.z : NEGV;
        float e = __expf(val - mx); se += e; sem += e * m4; semd += e * m4 * dv.z;
      }
      {
        float m4 = mrow * mj.w; float val = m4 > 0.f ? xv.w : NEGV;
        float e = __expf(val - mx); se += e; sem += e * m4; semd += e * m4 * dv.w;
      }
    }
#pragma unroll
    for (int o = 8; o >= 1; o >>= 1) {
      se += __shfl_xor(se, o, 16);
      sem += __shfl_xor(sem, o, 16);
      semd += __shfl_xor(semd, o, 16);
    }
    if (c == 0) {
      float md_row = semd / (sem + 1e-13f * se);
      md_rows[((size_t)b * H + h) * A + a] = md_row;
    }
  }

  // ---- depth bias (cols < V), in place ----
  {
    const float dref = (i0 < V) ? depth_value[(size_t)b0 * V + row]
                                : mean_depth[(size_t)b * A + (row - V)];
#pragma unroll
    for (int n = 0; n < 6; ++n) {
      int j = 4 * c + 64 * n;
      float4 xv = *(float4*)&xs[i][j];
      float4 dv = *(const float4*)&depth_value[(size_t)b0 * V + j];
      float bb;
      bb = fabsf(xv.x) * (__expf(-fabsf(dref - dv.x)) - BBC);
      if (i0 < V && (j + 0) == row) bb = 0.f;
      xv.x += bb;
      bb = fabsf(xv.y) * (__expf(-fabsf(dref - dv.y)) - BBC);
      if (i0 < V && (j + 1) == row) bb = 0.f;
      xv.y += bb;
      bb = fabsf(xv.z) * (__expf(-fabsf(dref - dv.z)) - BBC);
      if (i0 < V && (j + 2) == row) bb = 0.f;
      xv.z += bb;
      bb = fabsf(xv.w) * (__expf(-fabsf(dref - dv.w)) - BBC);
      if (i0 < V && (j + 3) == row) bb = 0.f;
      xv.w += bb;
      *(float4*)&xs[i][j] = xv;
    }
  }

  // ---- mask, write att_score, rowmax ----
  float mx = NEGV;
  float* srow = &att_score[((size_t)bh * S + row) * S];
#pragma unroll
  for (int n = 0; n < 12; ++n) {
    int j = 4 * c + 64 * n;
    float4 xv = *(float4*)&xs[i][j];
    float4 mj = *(const float4*)&mrowp[j];
    xv.x = (mrow * mj.x > 0.f) ? xv.x : NEGV; mx = fmaxf(mx, xv.x);
    xv.y = (mrow * mj.y > 0.f) ? xv.y : NEGV; mx = fmaxf(mx, xv.y);
    xv.z = (mrow * mj.z > 0.f) ? xv.z : NEGV; mx = fmaxf(mx, xv.z);
    xv.w = (mrow * mj.w > 0.f) ? xv.w : NEGV; mx = fmaxf(mx, xv.w);
    *(float4*)&xs[i][j] = xv;
    *(float4*)&srow[j] = xv;
  }
#pragma unroll
  for (int o = 8; o >= 1; o >>= 1) mx = fmaxf(mx, __shfl_xor(mx, o, 16));

  // ---- exp + sums ----
  float se = 0.f, sem = 0.f;
#pragma unroll
  for (int n = 0; n < 12; ++n) {
    int j = 4 * c + 64 * n;
    float4 xv = *(float4*)&xs[i][j];
    float4 mj = *(const float4*)&mrowp[j];
    float e;
    e = __expf(xv.x - mx); se += e; sem += e * (mrow * mj.x); xv.x = e;
    e = __expf(xv.y - mx); se += e; sem += e * (mrow * mj.y); xv.y = e;
    e = __expf(xv.z - mx); se += e; sem += e * (mrow * mj.z); xv.z = e;
    e = __expf(xv.w - mx); se += e; sem += e * (mrow * mj.w); xv.w = e;
    *(float4*)&xs[i][j] = xv;
  }
#pragma unroll
  for (int o = 8; o >= 1; o >>= 1) {
    se += __shfl_xor(se, o, 16);
    sem += __shfl_xor(sem, o, 16);
  }
  const float rden = 1.f / (sem + 1e-13f * se);

  // ---- normalize, write att_map ----
  float* prow = &att_map[((size_t)bh * S + row) * S];
#pragma unroll
  for (int n = 0; n < 12; ++n) {
    int j = 4 * c + 64 * n;
    float4 xv = *(float4*)&xs[i][j];
    float4 mj = *(const float4*)&mrowp[j];
    xv.x *= (mrow * mj.x) * rden;
    xv.y *= (mrow * mj.y) * rden;
    xv.z *= (mrow * mj.z) * rden;
    xv.w *= (mrow * mj.w) * rden;
    *(float4*)&xs[i][j] = xv;
    *(float4*)&prow[j] = xv;
  }
  __syncthreads();

  // ---- PV: ctx row into qh region (head layout) ----
  float4 acc = make_float4(0.f, 0.f, 0.f, 0.f);
  const float* vbase = &vh[(size_t)bh * S * D + 4 * c];
#pragma unroll 2
  for (int j4 = 0; j4 < S / 4; ++j4) {
    float4 p4 = *(float4*)&xs[i][j4 * 4];
    float4 v0 = *(const float4*)&vbase[(j4 * 4 + 0) * D];
    float4 v1 = *(const float4*)&vbase[(j4 * 4 + 1) * D];
    float4 v2 = *(const float4*)&vbase[(j4 * 4 + 2) * D];
    float4 v3 = *(const float4*)&vbase[(j4 * 4 + 3) * D];
    acc.x += p4.x * v0.x + p4.y * v1.x + p4.z * v2.x + p4.w * v3.x;
    acc.y += p4.x * v0.y + p4.y * v1.y + p4.z * v2.y + p4.w * v3.y;
    acc.z += p4.x * v0.z + p4.y * v1.z + p4.z * v2.z + p4.w * v3.z;
    acc.w += p4.x * v0.w + p4.y * v1.w + p4.z * v2.w + p4.w * v3.w;
  }
  *(float4*)&qh[((size_t)bh * S + row) * D + 4 * c] = acc;
}

// ---------------- md finalize: deterministic block reduction per b ----------------
__global__ __launch_bounds__(256) void md_finalize(const float* __restrict__ md_rows,
                                                   const float* __restrict__ va_a_mask,
                                                   float* __restrict__ md_out) {
  __shared__ float red0[256];
  __shared__ float red1[256];
  const int b = blockIdx.x;
  const int t = threadIdx.x;
  float s1 = 0.f, s2 = 0.f;
  for (int u = t; u < H * A; u += 256) s1 += md_rows[(size_t)b * H * A + u];
  for (int u = t; u < A; u += 256) s2 += va_a_mask[(size_t)b * A + u];
  red0[t] = s1; red1[t] = s2;
  __syncthreads();
  for (int o = 128; o > 0; o >>= 1) {
    if (t < o) { red0[t] += red0[t + o]; red1[t] += red1[t + o]; }
    __syncthreads();
  }
  const float val = red0[0] / ((float)H * red1[0]);
  for (int u = t; u < A; u += 256) md_out[(size_t)b * A + u] = val;
}

extern "C" void kernel_launch(void* const* d_in, const int* in_sizes, int n_in,
                              void* d_out, int out_size, void* d_ws, size_t ws_size,
                              hipStream_t stream) {
  const float* q           = (const float*)d_in[0];
  const float* k           = (const float*)d_in[1];
  const float* v           = (const float*)d_in[2];
  const float* mask        = (const float*)d_in[3];
  const float* depth_value = (const float*)d_in[4];
  const float* va_a_mask   = (const float*)d_in[7];
  const float* mean_depth  = (const float*)d_in[8];
  const float* Wq = (const float*)d_in[9];
  const float* bq = (const float*)d_in[10];
  const float* Wk = (const float*)d_in[11];
  const float* bk = (const float*)d_in[12];
  const float* Wv = (const float*)d_in[13];
  const float* bv = (const float*)d_in[14];
  const float* Wo = (const float*)d_in[15];
  const float* bo = (const float*)d_in[16];

  float* ws = (float*)d_ws;
  float* qh = ws;                 // (B,H,S,D), later reused as ctx
  float* kh = ws + N_QH;
  float* vh = ws + 2 * N_QH;
  float* md_rows = ws + 3 * N_QH; // (B,H,A)

  float* out       = (float*)d_out;                       // (B,S,HD)
  float* att_score = out + (size_t)B * S * HD;            // (B,H,S,S)
  float* att_map   = att_score + (size_t)B * H * S * S;   // (B,H,S,S)
  float* md_out    = att_map + (size_t)B * H * S * S;     // (B,A)

  dim3 gg(96, 8);
  gemm512<0, 1><<<gg, 256, 0, stream>>>(q, Wq, bq, qh);
  gemm512<0, 1><<<gg, 256, 0, stream>>>(k, Wk, bk, kh);
  gemm512<0, 1><<<gg, 256, 0, stream>>>(v, Wv, bv, vh);
  attn_kernel<<<B * H * (S / 16), 256, 0, stream>>>(qh, kh, vh, mask, depth_value,
                                                    mean_depth, att_score, att_map,
                                                    md_rows);
  gemm512<1, 0><<<gg, 256, 0, stream>>>(qh, Wo, bo, out);
  md_finalize<<<B, 256, 0, stream>>>(md_rows, va_a_mask, md_out);
}

// Round 2
// 456.741 us; speedup vs baseline: 1.8509x; 1.8509x over previous
//
#include <hip/hip_runtime.h>
#include <hip/hip_bf16.h>
#include <cstdint>
#include <cstddef>

namespace {
constexpr int B  = 8;
constexpr int S  = 768;
constexpr int V  = 384;
constexpr int A  = 384;
constexpr int H  = 8;
constexpr int D  = 64;
constexpr int HD = 512;
constexpr float SCALE = 0.125f;       // d^-0.5, d=64
constexpr float BBC   = 0.6f;
constexpr float NEGV  = -1000000000.0f;
constexpr size_t N_QH = (size_t)B * H * S * D;   // 3145728
}

// ---------------- GEMM: Y = X @ W + bias  (M=6144, N=512, K=512) ----------------
template <int XHEAD, int YHEAD>
__global__ __launch_bounds__(256) void gemm512(const float* __restrict__ X,
                                               const float* __restrict__ W,
                                               const float* __restrict__ bias,
                                               float* __restrict__ Y) {
  __shared__ float As[16][68];
  __shared__ float Bs[16][64];
  const int m0 = blockIdx.x * 64;
  const int n0 = blockIdx.y * 64;
  const int t  = threadIdx.x;
  const int tx = t & 15, ty = t >> 4;
  float acc[4][4] = {};
  for (int k0 = 0; k0 < 512; k0 += 16) {
#pragma unroll
    for (int u = 0; u < 4; ++u) {
      int idx = t + u * 256;
      int kk = idx & 15, mm = idx >> 4;
      int r = m0 + mm, k = k0 + kk;
      size_t xaddr;
      if (XHEAD) {
        int bb = r / S, s = r - bb * S;
        xaddr = ((size_t)(bb * H + (k >> 6)) * S + s) * D + (k & 63);
      } else {
        xaddr = (size_t)r * 512 + k;
      }
      As[kk][mm] = X[xaddr];
    }
#pragma unroll
    for (int u = 0; u < 4; ++u) {
      int idx = t + u * 256;
      int nn = idx & 63, kk = idx >> 6;
      Bs[kk][nn] = W[(size_t)(k0 + kk) * 512 + n0 + nn];
    }
    __syncthreads();
#pragma unroll
    for (int kk = 0; kk < 16; ++kk) {
      float4 a4 = *(float4*)&As[kk][ty * 4];
      float4 b4 = *(float4*)&Bs[kk][tx * 4];
      float a[4] = {a4.x, a4.y, a4.z, a4.w};
      float bb[4] = {b4.x, b4.y, b4.z, b4.w};
#pragma unroll
      for (int i = 0; i < 4; ++i)
#pragma unroll
        for (int j = 0; j < 4; ++j) acc[i][j] += a[i] * bb[j];
    }
    __syncthreads();
  }
  const int c0 = n0 + tx * 4;
  float4 bi = *(const float4*)&bias[c0];
#pragma unroll
  for (int i = 0; i < 4; ++i) {
    int r = m0 + ty * 4 + i;
    float4 o;
    o.x = acc[i][0] + bi.x;
    o.y = acc[i][1] + bi.y;
    o.z = acc[i][2] + bi.z;
    o.w = acc[i][3] + bi.w;
    if (YHEAD) {
      int bb = r / S, s = r - bb * S;
      *(float4*)&Y[((size_t)(bb * H + (c0 >> 6)) * S + s) * D + (c0 & 63)] = o;
    } else {
      *(float4*)&Y[(size_t)r * 512 + c0] = o;
    }
  }
}

// ---------------- score: att_score = mask(scale*QK^T + depth_bias) ----------------
// grid (12 qt, 12 kt, 64 bh); block 256 = 16x16; thread computes 4x4 tile
__global__ __launch_bounds__(256) void score_kernel(
    const float* __restrict__ qh, const float* __restrict__ kh,
    const float* __restrict__ mask, const float* __restrict__ depth_value,
    const float* __restrict__ mean_depth, float* __restrict__ att_score)
{
  __shared__ float Qs[64][68];
  __shared__ float Ks[64][68];
  const int qt = blockIdx.x, kt = blockIdx.y, bh = blockIdx.z;
  const int b = bh >> 3, b0 = b >> 2;
  const int q0 = qt << 6, k0 = kt << 6;
  const int t = threadIdx.x;
  const int tx = t & 15, ty = t >> 4;
  // stage Q,K transposed: [d][row]; row = t&63 gives conflict-free LDS stores
  {
    const int r = t & 63;
    const int dc = t >> 6;  // 0..3
#pragma unroll
    for (int u = 0; u < 4; ++u) {
      const int d0 = (u * 4 + dc) * 4;
      float4 qv = *(const float4*)&qh[((size_t)bh * S + q0 + r) * D + d0];
      Qs[d0 + 0][r] = qv.x; Qs[d0 + 1][r] = qv.y;
      Qs[d0 + 2][r] = qv.z; Qs[d0 + 3][r] = qv.w;
      float4 kv = *(const float4*)&kh[((size_t)bh * S + k0 + r) * D + d0];
      Ks[d0 + 0][r] = kv.x; Ks[d0 + 1][r] = kv.y;
      Ks[d0 + 2][r] = kv.z; Ks[d0 + 3][r] = kv.w;
    }
  }
  __syncthreads();
  float acc[4][4] = {};
#pragma unroll 16
  for (int kk = 0; kk < 64; ++kk) {
    float4 a4 = *(float4*)&Qs[kk][ty * 4];
    float4 b4 = *(float4*)&Ks[kk][tx * 4];
    float a[4] = {a4.x, a4.y, a4.z, a4.w};
    float bb[4] = {b4.x, b4.y, b4.z, b4.w};
#pragma unroll
    for (int i = 0; i < 4; ++i)
#pragma unroll
      for (int j = 0; j < 4; ++j) acc[i][j] += a[i] * bb[j];
  }
  // epilogue
  const float* mb = &mask[(size_t)b * S];
  const int c0 = k0 + tx * 4;
  const float4 mc = *(const float4*)&mb[c0];
  float4 dv4 = make_float4(0.f, 0.f, 0.f, 0.f);
  if (kt < 6) dv4 = *(const float4*)&depth_value[(size_t)b0 * V + c0];
#pragma unroll
  for (int i = 0; i < 4; ++i) {
    const int row = q0 + ty * 4 + i;
    const float mr = mb[row];
    float4 x;
    x.x = acc[i][0] * SCALE; x.y = acc[i][1] * SCALE;
    x.z = acc[i][2] * SCALE; x.w = acc[i][3] * SCALE;
    if (kt < 6) {
      const float dref = (row < V) ? depth_value[(size_t)b0 * V + row]
                                   : mean_depth[(size_t)b * A + (row - V)];
      float g, bb;
      g = __expf(-fabsf(dref - dv4.x)) - BBC; bb = fabsf(x.x) * g;
      if (row == c0 + 0) bb = 0.f; x.x += bb;
      g = __expf(-fabsf(dref - dv4.y)) - BBC; bb = fabsf(x.y) * g;
      if (row == c0 + 1) bb = 0.f; x.y += bb;
      g = __expf(-fabsf(dref - dv4.z)) - BBC; bb = fabsf(x.z) * g;
      if (row == c0 + 2) bb = 0.f; x.z += bb;
      g = __expf(-fabsf(dref - dv4.w)) - BBC; bb = fabsf(x.w) * g;
      if (row == c0 + 3) bb = 0.f; x.w += bb;
    }
    x.x = (mr * mc.x > 0.f) ? x.x : NEGV;
    x.y = (mr * mc.y > 0.f) ? x.y : NEGV;
    x.z = (mr * mc.z > 0.f) ? x.z : NEGV;
    x.w = (mr * mc.w > 0.f) ? x.w : NEGV;
    *(float4*)&att_score[((size_t)bh * S + row) * S + c0] = x;
  }
}

// ---------------- stats: per-row softmax stats + AV/md stats ----------------
// one wave per row; block = 4 waves; grid = B*H*S/4
__global__ __launch_bounds__(256) void stats_kernel(
    const float* __restrict__ att_score, const float* __restrict__ mask,
    const float* __restrict__ depth_value, const float* __restrict__ mean_depth,
    float2* __restrict__ row_stats, float* __restrict__ md_rows)
{
  const int gr = blockIdx.x * 4 + (threadIdx.x >> 6);
  const int c = threadIdx.x & 63;
  const int bh = gr / S;
  const int row = gr - bh * S;
  const int b = bh >> 3, b0 = b >> 2;
  const float* srow = &att_score[(size_t)gr * S];
  const float* mb = &mask[(size_t)b * S];
  const float mr = mb[row];
  float4 xv[3], mv[3];
#pragma unroll
  for (int u = 0; u < 3; ++u) {
    xv[u] = *(const float4*)&srow[u * 256 + 4 * c];
    mv[u] = *(const float4*)&mb[u * 256 + 4 * c];
  }
  float mx = NEGV;
#pragma unroll
  for (int u = 0; u < 3; ++u) {
    mx = fmaxf(mx, fmaxf(fmaxf(xv[u].x, xv[u].y), fmaxf(xv[u].z, xv[u].w)));
  }
#pragma unroll
  for (int o = 32; o >= 1; o >>= 1) mx = fmaxf(mx, __shfl_xor(mx, o));
  float se = 0.f, sem = 0.f;
#pragma unroll
  for (int u = 0; u < 3; ++u) {
    float e;
    e = __expf(xv[u].x - mx); se += e; sem += e * (mr * mv[u].x);
    e = __expf(xv[u].y - mx); se += e; sem += e * (mr * mv[u].y);
    e = __expf(xv[u].z - mx); se += e; sem += e * (mr * mv[u].z);
    e = __expf(xv[u].w - mx); se += e; sem += e * (mr * mv[u].w);
  }
#pragma unroll
  for (int o = 32; o >= 1; o >>= 1) {
    se += __shfl_xor(se, o);
    sem += __shfl_xor(sem, o);
  }
  if (c == 0) row_stats[gr] = make_float2(mx, 1.f / (sem + 1e-13f * se));

  // ---- AV pre-bias stats for md (audio rows only, cols < V) ----
  if (row >= V) {
    const int a = row - V;
    const float mdv = mean_depth[(size_t)b * A + a];
    // invert the depth bias: pre = post / (1 + sign(post)*g)
    float4 dv0 = *(const float4*)&depth_value[(size_t)b0 * V + 4 * c];
    float g0[4], pre0[4], pm0[4];
    g0[0] = __expf(-fabsf(mdv - dv0.x)) - BBC;
    g0[1] = __expf(-fabsf(mdv - dv0.y)) - BBC;
    g0[2] = __expf(-fabsf(mdv - dv0.z)) - BBC;
    g0[3] = __expf(-fabsf(mdv - dv0.w)) - BBC;
    float xr0[4] = {xv[0].x, xv[0].y, xv[0].z, xv[0].w};
    float mm0[4] = {mv[0].x, mv[0].y, mv[0].z, mv[0].w};
#pragma unroll
    for (int j = 0; j < 4; ++j) {
      float post = xr0[j];
      float pre = post / (post > 0.f ? 1.f + g0[j] : 1.f - g0[j]);
      pm0[j] = mr * mm0[j];
      pre0[j] = (pm0[j] > 0.f) ? pre : NEGV;
    }
    float4 dv1 = make_float4(0.f, 0.f, 0.f, 0.f);
    float pre1[4] = {NEGV, NEGV, NEGV, NEGV};
    float pm1[4] = {0.f, 0.f, 0.f, 0.f};
    if (c < 32) {
      dv1 = *(const float4*)&depth_value[(size_t)b0 * V + 256 + 4 * c];
      float g1[4];
      g1[0] = __expf(-fabsf(mdv - dv1.x)) - BBC;
      g1[1] = __expf(-fabsf(mdv - dv1.y)) - BBC;
      g1[2] = __expf(-fabsf(mdv - dv1.z)) - BBC;
      g1[3] = __expf(-fabsf(mdv - dv1.w)) - BBC;
      float xr1[4] = {xv[1].x, xv[1].y, xv[1].z, xv[1].w};
      float mm1[4] = {mv[1].x, mv[1].y, mv[1].z, mv[1].w};
#pragma unroll
      for (int j = 0; j < 4; ++j) {
        float post = xr1[j];
        float pre = post / (post > 0.f ? 1.f + g1[j] : 1.f - g1[j]);
        pm1[j] = mr * mm1[j];
        pre1[j] = (pm1[j] > 0.f) ? pre : NEGV;
      }
    }
    float mxa = NEGV;
#pragma unroll
    for (int j = 0; j < 4; ++j) mxa = fmaxf(mxa, fmaxf(pre0[j], pre1[j]));
#pragma unroll
    for (int o = 32; o >= 1; o >>= 1) mxa = fmaxf(mxa, __shfl_xor(mxa, o));
    float se2 = 0.f, sem2 = 0.f, smd2 = 0.f;
    float dvr0[4] = {dv0.x, dv0.y, dv0.z, dv0.w};
    float dvr1[4] = {dv1.x, dv1.y, dv1.z, dv1.w};
#pragma unroll
    for (int j = 0; j < 4; ++j) {
      float e = __expf(pre0[j] - mxa);
      se2 += e; sem2 += e * pm0[j]; smd2 += e * pm0[j] * dvr0[j];
    }
    if (c < 32) {
#pragma unroll
      for (int j = 0; j < 4; ++j) {
        float e = __expf(pre1[j] - mxa);
        se2 += e; sem2 += e * pm1[j]; smd2 += e * pm1[j] * dvr1[j];
      }
    }
#pragma unroll
    for (int o = 32; o >= 1; o >>= 1) {
      se2 += __shfl_xor(se2, o);
      sem2 += __shfl_xor(sem2, o);
      smd2 += __shfl_xor(smd2, o);
    }
    if (c == 0) md_rows[(size_t)bh * A + a] = smd2 / (sem2 + 1e-13f * se2);
  }
}

// ---------------- map + PV: att_map write + ctx = att_map @ V ----------------
// grid (24 row-tiles of 32, 64 bh); block 256 = 16x16
__global__ __launch_bounds__(256) void map_pv_kernel(
    const float* __restrict__ att_score, const float* __restrict__ vh,
    const float* __restrict__ mask, const float2* __restrict__ row_stats,
    float* __restrict__ att_map, float* __restrict__ ctx)
{
  __shared__ float Ps[64][33];   // [col][row] transposed
  __shared__ float Vs[64][68];   // [col][d]
  const int rt = blockIdx.x, bh = blockIdx.y;
  const int b = bh >> 3;
  const int r0 = rt * 32;
  const int t = threadIdx.x, tx = t & 15, ty = t >> 4;
  const float* mb = &mask[(size_t)b * S];
  float2 st[2]; float mr[2];
#pragma unroll
  for (int u = 0; u < 2; ++u) {
    st[u] = row_stats[(size_t)bh * S + r0 + u * 16 + ty];
    mr[u] = mb[r0 + u * 16 + ty];
  }
  float acc0[4] = {}, acc1[4] = {};
  for (int ck = 0; ck < 12; ++ck) {
    const int c0 = ck * 64;
    const float4 mc = *(const float4*)&mb[c0 + 4 * tx];
    __syncthreads();
#pragma unroll
    for (int u = 0; u < 2; ++u) {
      const int r = u * 16 + ty;
      const size_t grow = (size_t)bh * S + r0 + r;
      float4 xv = *(const float4*)&att_score[grow * S + c0 + 4 * tx];
      float4 p;
      p.x = __expf(xv.x - st[u].x) * (mr[u] * mc.x) * st[u].y;
      p.y = __expf(xv.y - st[u].x) * (mr[u] * mc.y) * st[u].y;
      p.z = __expf(xv.z - st[u].x) * (mr[u] * mc.z) * st[u].y;
      p.w = __expf(xv.w - st[u].x) * (mr[u] * mc.w) * st[u].y;
      *(float4*)&att_map[grow * S + c0 + 4 * tx] = p;
      Ps[4 * tx + 0][r] = p.x; Ps[4 * tx + 1][r] = p.y;
      Ps[4 * tx + 2][r] = p.z; Ps[4 * tx + 3][r] = p.w;
    }
#pragma unroll
    for (int u = 0; u < 4; ++u) {
      const int j = u * 16 + ty;
      *(float4*)&Vs[j][4 * tx] =
          *(const float4*)&vh[((size_t)bh * S + c0 + j) * D + 4 * tx];
    }
    __syncthreads();
#pragma unroll 16
    for (int kk = 0; kk < 64; ++kk) {
      float a0 = Ps[kk][ty];
      float a1 = Ps[kk][ty + 16];
      float4 b4 = *(float4*)&Vs[kk][4 * tx];
      acc0[0] += a0 * b4.x; acc0[1] += a0 * b4.y;
      acc0[2] += a0 * b4.z; acc0[3] += a0 * b4.w;
      acc1[0] += a1 * b4.x; acc1[1] += a1 * b4.y;
      acc1[2] += a1 * b4.z; acc1[3] += a1 * b4.w;
    }
  }
  {
    float4 o0 = make_float4(acc0[0], acc0[1], acc0[2], acc0[3]);
    float4 o1 = make_float4(acc1[0], acc1[1], acc1[2], acc1[3]);
    *(float4*)&ctx[((size_t)bh * S + r0 + ty) * D + 4 * tx] = o0;
    *(float4*)&ctx[((size_t)bh * S + r0 + ty + 16) * D + 4 * tx] = o1;
  }
}

// ---------------- md finalize ----------------
__global__ __launch_bounds__(256) void md_finalize(const float* __restrict__ md_rows,
                                                   const float* __restrict__ va_a_mask,
                                                   float* __restrict__ md_out) {
  __shared__ float red0[256];
  __shared__ float red1[256];
  const int b = blockIdx.x;
  const int t = threadIdx.x;
  float s1 = 0.f, s2 = 0.f;
  for (int u = t; u < H * A; u += 256) s1 += md_rows[(size_t)b * H * A + u];
  for (int u = t; u < A; u += 256) s2 += va_a_mask[(size_t)b * A + u];
  red0[t] = s1; red1[t] = s2;
  __syncthreads();
  for (int o = 128; o > 0; o >>= 1) {
    if (t < o) { red0[t] += red0[t + o]; red1[t] += red1[t + o]; }
    __syncthreads();
  }
  const float val = red0[0] / ((float)H * red1[0]);
  for (int u = t; u < A; u += 256) md_out[(size_t)b * A + u] = val;
}

extern "C" void kernel_launch(void* const* d_in, const int* in_sizes, int n_in,
                              void* d_out, int out_size, void* d_ws, size_t ws_size,
                              hipStream_t stream) {
  const float* q           = (const float*)d_in[0];
  const float* k           = (const float*)d_in[1];
  const float* v           = (const float*)d_in[2];
  const float* mask        = (const float*)d_in[3];
  const float* depth_value = (const float*)d_in[4];
  const float* va_a_mask   = (const float*)d_in[7];
  const float* mean_depth  = (const float*)d_in[8];
  const float* Wq = (const float*)d_in[9];
  const float* bq = (const float*)d_in[10];
  const float* Wk = (const float*)d_in[11];
  const float* bk = (const float*)d_in[12];
  const float* Wv = (const float*)d_in[13];
  const float* bv = (const float*)d_in[14];
  const float* Wo = (const float*)d_in[15];
  const float* bo = (const float*)d_in[16];

  float* ws = (float*)d_ws;
  float* qh = ws;                    // (B,H,S,D), reused as ctx
  float* kh = ws + N_QH;
  float* vh = ws + 2 * N_QH;
  float* md_rows = ws + 3 * N_QH;    // B*H*A
  float2* row_stats = (float2*)(ws + 3 * N_QH + (size_t)B * H * A);  // B*H*S

  float* out       = (float*)d_out;
  float* att_score = out + (size_t)B * S * HD;
  float* att_map   = att_score + (size_t)B * H * S * S;
  float* md_out    = att_map + (size_t)B * H * S * S;

  dim3 gg(96, 8);
  gemm512<0, 1><<<gg, 256, 0, stream>>>(q, Wq, bq, qh);
  gemm512<0, 1><<<gg, 256, 0, stream>>>(k, Wk, bk, kh);
  gemm512<0, 1><<<gg, 256, 0, stream>>>(v, Wv, bv, vh);
  score_kernel<<<dim3(12, 12, 64), 256, 0, stream>>>(qh, kh, mask, depth_value,
                                                     mean_depth, att_score);
  stats_kernel<<<B * H * S / 4, 256, 0, stream>>>(att_score, mask, depth_value,
                                                  mean_depth, row_stats, md_rows);
  map_pv_kernel<<<dim3(24, 64), 256, 0, stream>>>(att_score, vh, mask, row_stats,
                                                  att_map, qh);
  gemm512<1, 0><<<gg, 256, 0, stream>>>(qh, Wo, bo, out);
  md_finalize<<<B, 256, 0, stream>>>(md_rows, va_a_mask, md_out);
}

// Round 3
// 395.778 us; speedup vs baseline: 2.1360x; 1.1540x over previous
//
#include <hip/hip_runtime.h>
#include <hip/hip_bf16.h>
#include <cstdint>
#include <cstddef>

namespace {
constexpr int B  = 8;
constexpr int S  = 768;
constexpr int V  = 384;
constexpr int A  = 384;
constexpr int H  = 8;
constexpr int D  = 64;
constexpr int HD = 512;
constexpr float SCALE = 0.125f;       // d^-0.5, d=64
constexpr float BBC   = 0.6f;
constexpr float NEGV  = -1000000000.0f;
constexpr size_t N_QH = (size_t)B * H * S * D;   // 3145728
}

using short8 = __attribute__((ext_vector_type(8))) short;
using f32x4  = __attribute__((ext_vector_type(4))) float;

static __device__ __forceinline__ unsigned short f2bf(float f) {
  union { float f; unsigned int u; } v; v.f = f;
  unsigned int r = v.u + 0x7FFFu + ((v.u >> 16) & 1u);
  return (unsigned short)(r >> 16);
}
static __device__ __forceinline__ float bf2f(unsigned short h) {
  union { unsigned int u; float f; } v; v.u = ((unsigned int)h) << 16;
  return v.f;
}
static __device__ __forceinline__ f32x4 mfma16(short8 a, short8 b, f32x4 c) {
  return __builtin_amdgcn_mfma_f32_16x16x32_bf16(a, b, c, 0, 0, 0);
}

// ---------------- GEMM: Y = X @ W + bias  (M=6144, N=512, K=512) ----------------
// XHEAD: read X from head layout (B,H,S,D). OMODE: 0 = f32 row-major,
// 2 = bf16 hi/lo head-layout, 3 = bf16 single head-layout.
template <int XHEAD, int OMODE>
__global__ __launch_bounds__(256) void gemm512(const float* __restrict__ X,
                                               const float* __restrict__ W,
                                               const float* __restrict__ bias,
                                               float* __restrict__ Yf,
                                               unsigned short* __restrict__ Yhi,
                                               unsigned short* __restrict__ Ylo) {
  __shared__ float As[16][68];
  __shared__ float Bs[16][64];
  const int m0 = blockIdx.x * 64;
  const int n0 = blockIdx.y * 64;
  const int t  = threadIdx.x;
  const int tx = t & 15, ty = t >> 4;
  float acc[4][4] = {};
  for (int k0 = 0; k0 < 512; k0 += 16) {
#pragma unroll
    for (int u = 0; u < 4; ++u) {
      int idx = t + u * 256;
      int kk = idx & 15, mm = idx >> 4;
      int r = m0 + mm, k = k0 + kk;
      size_t xaddr;
      if (XHEAD) {
        int bb = r / S, s = r - bb * S;
        xaddr = ((size_t)(bb * H + (k >> 6)) * S + s) * D + (k & 63);
      } else {
        xaddr = (size_t)r * 512 + k;
      }
      As[kk][mm] = X[xaddr];
    }
#pragma unroll
    for (int u = 0; u < 4; ++u) {
      int idx = t + u * 256;
      int nn = idx & 63, kk = idx >> 6;
      Bs[kk][nn] = W[(size_t)(k0 + kk) * 512 + n0 + nn];
    }
    __syncthreads();
#pragma unroll
    for (int kk = 0; kk < 16; ++kk) {
      float4 a4 = *(float4*)&As[kk][ty * 4];
      float4 b4 = *(float4*)&Bs[kk][tx * 4];
      float a[4] = {a4.x, a4.y, a4.z, a4.w};
      float bb[4] = {b4.x, b4.y, b4.z, b4.w};
#pragma unroll
      for (int i = 0; i < 4; ++i)
#pragma unroll
        for (int j = 0; j < 4; ++j) acc[i][j] += a[i] * bb[j];
    }
    __syncthreads();
  }
  const int c0 = n0 + tx * 4;
  float4 bi = *(const float4*)&bias[c0];
#pragma unroll
  for (int i = 0; i < 4; ++i) {
    int r = m0 + ty * 4 + i;
    float o[4];
    o[0] = acc[i][0] + bi.x; o[1] = acc[i][1] + bi.y;
    o[2] = acc[i][2] + bi.z; o[3] = acc[i][3] + bi.w;
    if (OMODE == 0) {
      *(float4*)&Yf[(size_t)r * 512 + c0] = make_float4(o[0], o[1], o[2], o[3]);
    } else {
      int bb = r / S, s = r - bb * S;
      size_t addr = ((size_t)(bb * H + (c0 >> 6)) * S + s) * D + (c0 & 63);
      unsigned short h[4];
#pragma unroll
      for (int j = 0; j < 4; ++j) h[j] = f2bf(o[j]);
      uint2 hp = make_uint2((unsigned)h[0] | ((unsigned)h[1] << 16),
                            (unsigned)h[2] | ((unsigned)h[3] << 16));
      *(uint2*)&Yhi[addr] = hp;
      if (OMODE == 2) {
        unsigned short l[4];
#pragma unroll
        for (int j = 0; j < 4; ++j) l[j] = f2bf(o[j] - bf2f(h[j]));
        uint2 lp = make_uint2((unsigned)l[0] | ((unsigned)l[1] << 16),
                              (unsigned)l[2] | ((unsigned)l[3] << 16));
        *(uint2*)&Ylo[addr] = lp;
      }
    }
  }
}

// ---------------- transpose v: vh[bh][s][d] -> vhT[bh][d][s] (bf16) ----------------
__global__ __launch_bounds__(256) void transpose_v(const unsigned short* __restrict__ vh,
                                                   unsigned short* __restrict__ vhT) {
  __shared__ unsigned short tile[64][72];
  const int st = blockIdx.x, bh = blockIdx.y;
  const int t = threadIdx.x;
  {
    const int r = t & 63;
    const int d0 = (t >> 6) * 16;
    const size_t src = ((size_t)bh * S + st * 64 + r) * D + d0;
    *(short8*)&tile[r][d0]     = *(const short8*)&vh[src];
    *(short8*)&tile[r][d0 + 8] = *(const short8*)&vh[src + 8];
  }
  __syncthreads();
  {
    const int d = t & 63;
    const int s0c = (t >> 6) * 16;
    unsigned short ov[16];
#pragma unroll
    for (int j = 0; j < 16; ++j) ov[j] = tile[s0c + j][d];
    const size_t dst = ((size_t)bh * D + d) * S + st * 64 + s0c;
    *(short8*)&vhT[dst]     = *(short8*)&ov[0];
    *(short8*)&vhT[dst + 8] = *(short8*)&ov[8];
  }
}

// ---------------- score: att_score = mask(scale*QK^T + depth_bias) via split-bf16 MFMA ----
// grid (12 qt, 12 kt, 64 bh); block 256 = 4 waves (2x2 of 32x32)
__global__ __launch_bounds__(256) void score_mfma(
    const unsigned short* __restrict__ qh_hi, const unsigned short* __restrict__ qh_lo,
    const unsigned short* __restrict__ kh_hi, const unsigned short* __restrict__ kh_lo,
    const float* __restrict__ mask, const float* __restrict__ depth_value,
    const float* __restrict__ mean_depth, float* __restrict__ att_score)
{
  const int qt = blockIdx.x, kt = blockIdx.y, bh = blockIdx.z;
  const int b = bh >> 3, b0 = b >> 2;
  const int q0 = qt << 6, k0 = kt << 6;
  const int t = threadIdx.x;
  const int wave = t >> 6, lane = t & 63;
  const int wr = wave >> 1, wc = wave & 1;
  const int l15 = lane & 15, g = lane >> 4;

  f32x4 acc[2][2] = {};  // [m-tile][n-tile]
#pragma unroll
  for (int ks = 0; ks < 2; ++ks) {
    const int dofs = ks * 32 + g * 8;
    short8 ah[2], al[2], bh_[2], bl[2];
#pragma unroll
    for (int tm = 0; tm < 2; ++tm) {
      const size_t rq = ((size_t)bh * S + q0 + wr * 32 + tm * 16 + l15) * D + dofs;
      ah[tm] = *(const short8*)&qh_hi[rq];
      al[tm] = *(const short8*)&qh_lo[rq];
    }
#pragma unroll
    for (int tn = 0; tn < 2; ++tn) {
      const size_t rk = ((size_t)bh * S + k0 + wc * 32 + tn * 16 + l15) * D + dofs;
      bh_[tn] = *(const short8*)&kh_hi[rk];
      bl[tn] = *(const short8*)&kh_lo[rk];
    }
#pragma unroll
    for (int tm = 0; tm < 2; ++tm)
#pragma unroll
      for (int tn = 0; tn < 2; ++tn) {
        acc[tm][tn] = mfma16(al[tm], bh_[tn], acc[tm][tn]);
        acc[tm][tn] = mfma16(ah[tm], bl[tn], acc[tm][tn]);
        acc[tm][tn] = mfma16(ah[tm], bh_[tn], acc[tm][tn]);
      }
  }

  const float* mb = &mask[(size_t)b * S];
  const bool dobias = (kt < 6);
  float dvc[2], mcc[2];
#pragma unroll
  for (int tn = 0; tn < 2; ++tn) {
    const int col = k0 + wc * 32 + tn * 16 + l15;
    mcc[tn] = mb[col];
    dvc[tn] = dobias ? depth_value[(size_t)b0 * V + col] : 0.f;
  }
#pragma unroll
  for (int tm = 0; tm < 2; ++tm) {
#pragma unroll
    for (int r = 0; r < 4; ++r) {
      const int row = q0 + wr * 32 + tm * 16 + g * 4 + r;
      const float mr = mb[row];
      float dref = 0.f;
      if (dobias)
        dref = (row < V) ? depth_value[(size_t)b0 * V + row]
                         : mean_depth[(size_t)b * A + (row - V)];
#pragma unroll
      for (int tn = 0; tn < 2; ++tn) {
        const int col = k0 + wc * 32 + tn * 16 + l15;
        float x = acc[tm][tn][r] * SCALE;
        if (dobias) {
          float gg = __expf(-fabsf(dref - dvc[tn])) - BBC;
          float bias = fabsf(x) * gg;
          if (row == col) bias = 0.f;
          x += bias;
        }
        x = (mr * mcc[tn] > 0.f) ? x : NEGV;
        att_score[((size_t)bh * S + row) * S + col] = x;
      }
    }
  }
}

// ---------------- stats: per-row softmax stats + AV/md stats ----------------
__global__ __launch_bounds__(256) void stats_kernel(
    const float* __restrict__ att_score, const float* __restrict__ mask,
    const float* __restrict__ depth_value, const float* __restrict__ mean_depth,
    float2* __restrict__ row_stats, float* __restrict__ md_rows)
{
  const int gr = blockIdx.x * 4 + (threadIdx.x >> 6);
  const int c = threadIdx.x & 63;
  const int bh = gr / S;
  const int row = gr - bh * S;
  const int b = bh >> 3, b0 = b >> 2;
  const float* srow = &att_score[(size_t)gr * S];
  const float* mb = &mask[(size_t)b * S];
  const float mr = mb[row];
  float4 xv[3], mv[3];
#pragma unroll
  for (int u = 0; u < 3; ++u) {
    xv[u] = *(const float4*)&srow[u * 256 + 4 * c];
    mv[u] = *(const float4*)&mb[u * 256 + 4 * c];
  }
  float mx = NEGV;
#pragma unroll
  for (int u = 0; u < 3; ++u)
    mx = fmaxf(mx, fmaxf(fmaxf(xv[u].x, xv[u].y), fmaxf(xv[u].z, xv[u].w)));
#pragma unroll
  for (int o = 32; o >= 1; o >>= 1) mx = fmaxf(mx, __shfl_xor(mx, o));
  float se = 0.f, sem = 0.f;
#pragma unroll
  for (int u = 0; u < 3; ++u) {
    float e;
    e = __expf(xv[u].x - mx); se += e; sem += e * (mr * mv[u].x);
    e = __expf(xv[u].y - mx); se += e; sem += e * (mr * mv[u].y);
    e = __expf(xv[u].z - mx); se += e; sem += e * (mr * mv[u].z);
    e = __expf(xv[u].w - mx); se += e; sem += e * (mr * mv[u].w);
  }
#pragma unroll
  for (int o = 32; o >= 1; o >>= 1) {
    se += __shfl_xor(se, o);
    sem += __shfl_xor(sem, o);
  }
  if (c == 0) row_stats[gr] = make_float2(mx, 1.f / (sem + 1e-13f * se));

  if (row >= V) {
    const int a = row - V;
    const float mdv = mean_depth[(size_t)b * A + a];
    float4 dv0 = *(const float4*)&depth_value[(size_t)b0 * V + 4 * c];
    float g0[4], pre0[4], pm0[4];
    g0[0] = __expf(-fabsf(mdv - dv0.x)) - BBC;
    g0[1] = __expf(-fabsf(mdv - dv0.y)) - BBC;
    g0[2] = __expf(-fabsf(mdv - dv0.z)) - BBC;
    g0[3] = __expf(-fabsf(mdv - dv0.w)) - BBC;
    float xr0[4] = {xv[0].x, xv[0].y, xv[0].z, xv[0].w};
    float mm0[4] = {mv[0].x, mv[0].y, mv[0].z, mv[0].w};
#pragma unroll
    for (int j = 0; j < 4; ++j) {
      float post = xr0[j];
      float pre = post / (post > 0.f ? 1.f + g0[j] : 1.f - g0[j]);
      pm0[j] = mr * mm0[j];
      pre0[j] = (pm0[j] > 0.f) ? pre : NEGV;
    }
    float4 dv1 = make_float4(0.f, 0.f, 0.f, 0.f);
    float pre1[4] = {NEGV, NEGV, NEGV, NEGV};
    float pm1[4] = {0.f, 0.f, 0.f, 0.f};
    if (c < 32) {
      dv1 = *(const float4*)&depth_value[(size_t)b0 * V + 256 + 4 * c];
      float g1[4];
      g1[0] = __expf(-fabsf(mdv - dv1.x)) - BBC;
      g1[1] = __expf(-fabsf(mdv - dv1.y)) - BBC;
      g1[2] = __expf(-fabsf(mdv - dv1.z)) - BBC;
      g1[3] = __expf(-fabsf(mdv - dv1.w)) - BBC;
      float xr1[4] = {xv[1].x, xv[1].y, xv[1].z, xv[1].w};
      float mm1[4] = {mv[1].x, mv[1].y, mv[1].z, mv[1].w};
#pragma unroll
      for (int j = 0; j < 4; ++j) {
        float post = xr1[j];
        float pre = post / (post > 0.f ? 1.f + g1[j] : 1.f - g1[j]);
        pm1[j] = mr * mm1[j];
        pre1[j] = (pm1[j] > 0.f) ? pre : NEGV;
      }
    }
    float mxa = NEGV;
#pragma unroll
    for (int j = 0; j < 4; ++j) mxa = fmaxf(mxa, fmaxf(pre0[j], pre1[j]));
#pragma unroll
    for (int o = 32; o >= 1; o >>= 1) mxa = fmaxf(mxa, __shfl_xor(mxa, o));
    float se2 = 0.f, sem2 = 0.f, smd2 = 0.f;
    float dvr0[4] = {dv0.x, dv0.y, dv0.z, dv0.w};
    float dvr1[4] = {dv1.x, dv1.y, dv1.z, dv1.w};
#pragma unroll
    for (int j = 0; j < 4; ++j) {
      float e = __expf(pre0[j] - mxa);
      se2 += e; sem2 += e * pm0[j]; smd2 += e * pm0[j] * dvr0[j];
    }
    if (c < 32) {
#pragma unroll
      for (int j = 0; j < 4; ++j) {
        float e = __expf(pre1[j] - mxa);
        se2 += e; sem2 += e * pm1[j]; smd2 += e * pm1[j] * dvr1[j];
      }
    }
#pragma unroll
    for (int o = 32; o >= 1; o >>= 1) {
      se2 += __shfl_xor(se2, o);
      sem2 += __shfl_xor(sem2, o);
      smd2 += __shfl_xor(smd2, o);
    }
    if (c == 0) md_rows[(size_t)bh * A + a] = smd2 / (sem2 + 1e-13f * se2);
  }
}

// ---------------- map + PV via MFMA: att_map write + ctx = att_map @ V ----------------
// grid (24 row-tiles of 32, 64 bh); block 256 = 4 waves
__global__ __launch_bounds__(256) void map_pv_mfma(
    const float* __restrict__ att_score, const unsigned short* __restrict__ vhT,
    const float* __restrict__ mask, const float2* __restrict__ row_stats,
    float* __restrict__ att_map, float* __restrict__ ctx)
{
  __shared__ unsigned short Ps[32][72];
  const int rt = blockIdx.x, bh = blockIdx.y;
  const int b = bh >> 3;
  const int r0 = rt * 32;
  const int t = threadIdx.x;
  const int tx = t & 15, ty = t >> 4;
  const float* mb = &mask[(size_t)b * S];
  float2 st[2]; float mr[2];
#pragma unroll
  for (int u = 0; u < 2; ++u) {
    st[u] = row_stats[(size_t)bh * S + r0 + u * 16 + ty];
    mr[u] = mb[r0 + u * 16 + ty];
  }
  const int wave = t >> 6, lane = t & 63;
  const int wr = wave >> 1, wc = wave & 1;
  const int l15 = lane & 15, g = lane >> 4;

  f32x4 acc[2] = {};
  for (int ck = 0; ck < 12; ++ck) {
    const int c0 = ck * 64;
    __syncthreads();
    const float4 mc = *(const float4*)&mb[c0 + 4 * tx];
#pragma unroll
    for (int u = 0; u < 2; ++u) {
      const size_t grow = (size_t)bh * S + r0 + u * 16 + ty;
      float4 xv = *(const float4*)&att_score[grow * S + c0 + 4 * tx];
      float4 p;
      p.x = __expf(xv.x - st[u].x) * (mr[u] * mc.x) * st[u].y;
      p.y = __expf(xv.y - st[u].x) * (mr[u] * mc.y) * st[u].y;
      p.z = __expf(xv.z - st[u].x) * (mr[u] * mc.z) * st[u].y;
      p.w = __expf(xv.w - st[u].x) * (mr[u] * mc.w) * st[u].y;
      *(float4*)&att_map[grow * S + c0 + 4 * tx] = p;
      uint2 pk = make_uint2((unsigned)f2bf(p.x) | ((unsigned)f2bf(p.y) << 16),
                            (unsigned)f2bf(p.z) | ((unsigned)f2bf(p.w) << 16));
      *(uint2*)&Ps[u * 16 + ty][4 * tx] = pk;
    }
    __syncthreads();
#pragma unroll
    for (int ks = 0; ks < 2; ++ks) {
      short8 a = *(short8*)&Ps[wr * 16 + l15][ks * 32 + g * 8];
      const int sofs = c0 + ks * 32 + g * 8;
#pragma unroll
      for (int tn = 0; tn < 2; ++tn) {
        const int d = wc * 32 + tn * 16 + l15;
        short8 bf = *(const short8*)&vhT[((size_t)bh * D + d) * S + sofs];
        acc[tn] = mfma16(a, bf, acc[tn]);
      }
    }
  }
#pragma unroll
  for (int tn = 0; tn < 2; ++tn)
#pragma unroll
    for (int r = 0; r < 4; ++r) {
      const int row = r0 + wr * 16 + g * 4 + r;
      ctx[((size_t)bh * S + row) * D + wc * 32 + tn * 16 + l15] = acc[tn][r];
    }
}

// ---------------- md finalize ----------------
__global__ __launch_bounds__(256) void md_finalize(const float* __restrict__ md_rows,
                                                   const float* __restrict__ va_a_mask,
                                                   float* __restrict__ md_out) {
  __shared__ float red0[256];
  __shared__ float red1[256];
  const int b = blockIdx.x;
  const int t = threadIdx.x;
  float s1 = 0.f, s2 = 0.f;
  for (int u = t; u < H * A; u += 256) s1 += md_rows[(size_t)b * H * A + u];
  for (int u = t; u < A; u += 256) s2 += va_a_mask[(size_t)b * A + u];
  red0[t] = s1; red1[t] = s2;
  __syncthreads();
  for (int o = 128; o > 0; o >>= 1) {
    if (t < o) { red0[t] += red0[t + o]; red1[t] += red1[t + o]; }
    __syncthreads();
  }
  const float val = red0[0] / ((float)H * red1[0]);
  for (int u = t; u < A; u += 256) md_out[(size_t)b * A + u] = val;
}

extern "C" void kernel_launch(void* const* d_in, const int* in_sizes, int n_in,
                              void* d_out, int out_size, void* d_ws, size_t ws_size,
                              hipStream_t stream) {
  const float* q           = (const float*)d_in[0];
  const float* k           = (const float*)d_in[1];
  const float* v           = (const float*)d_in[2];
  const float* mask        = (const float*)d_in[3];
  const float* depth_value = (const float*)d_in[4];
  const float* va_a_mask   = (const float*)d_in[7];
  const float* mean_depth  = (const float*)d_in[8];
  const float* Wq = (const float*)d_in[9];
  const float* bq = (const float*)d_in[10];
  const float* Wk = (const float*)d_in[11];
  const float* bk = (const float*)d_in[12];
  const float* Wv = (const float*)d_in[13];
  const float* bv = (const float*)d_in[14];
  const float* Wo = (const float*)d_in[15];
  const float* bo = (const float*)d_in[16];

  char* wsb = (char*)d_ws;
  unsigned short* qh_hi = (unsigned short*)wsb;
  unsigned short* qh_lo = qh_hi + N_QH;
  float*          ctx   = (float*)wsb;              // aliases qh_hi/lo (dead after score)
  unsigned short* kh_hi = (unsigned short*)(wsb + N_QH * 4);
  unsigned short* kh_lo = kh_hi + N_QH;
  unsigned short* vh_bf = (unsigned short*)(wsb + 2 * N_QH * 4);
  unsigned short* vhT   = vh_bf + N_QH;
  float*  md_rows   = (float*)(wsb + 3 * N_QH * 4);           // B*H*A
  float2* row_stats = (float2*)(md_rows + (size_t)B * H * A); // B*H*S

  float* out       = (float*)d_out;
  float* att_score = out + (size_t)B * S * HD;
  float* att_map   = att_score + (size_t)B * H * S * S;
  float* md_out    = att_map + (size_t)B * H * S * S;

  dim3 gg(96, 8);
  gemm512<0, 2><<<gg, 256, 0, stream>>>(q, Wq, bq, nullptr, qh_hi, qh_lo);
  gemm512<0, 2><<<gg, 256, 0, stream>>>(k, Wk, bk, nullptr, kh_hi, kh_lo);
  gemm512<0, 3><<<gg, 256, 0, stream>>>(v, Wv, bv, nullptr, vh_bf, nullptr);
  transpose_v<<<dim3(12, 64), 256, 0, stream>>>(vh_bf, vhT);
  score_mfma<<<dim3(12, 12, 64), 256, 0, stream>>>(qh_hi, qh_lo, kh_hi, kh_lo, mask,
                                                   depth_value, mean_depth, att_score);
  stats_kernel<<<B * H * S / 4, 256, 0, stream>>>(att_score, mask, depth_value,
                                                  mean_depth, row_stats, md_rows);
  map_pv_mfma<<<dim3(24, 64), 256, 0, stream>>>(att_score, vhT, mask, row_stats,
                                                att_map, ctx);
  gemm512<1, 0><<<gg, 256, 0, stream>>>(ctx, Wo, bo, out, nullptr, nullptr);
  md_finalize<<<B, 256, 0, stream>>>(md_rows, va_a_mask, md_out);
}

// Round 4
// 360.515 us; speedup vs baseline: 2.3449x; 1.0978x over previous
//
#include <hip/hip_runtime.h>
#include <hip/hip_bf16.h>
#include <cstdint>
#include <cstddef>

namespace {
constexpr int B  = 8;
constexpr int S  = 768;
constexpr int V  = 384;
constexpr int A  = 384;
constexpr int H  = 8;
constexpr int D  = 64;
constexpr int HD = 512;
constexpr float SCALE = 0.125f;       // d^-0.5, d=64
constexpr float BBC   = 0.6f;
constexpr float NEGV  = -1000000000.0f;
constexpr size_t N_QH = (size_t)B * H * S * D;   // 3145728
}

using short8 = __attribute__((ext_vector_type(8))) short;
using f32x4  = __attribute__((ext_vector_type(4))) float;

static __device__ __forceinline__ unsigned short f2bf(float f) {
  union { float f; unsigned int u; } v; v.f = f;
  unsigned int r = v.u + 0x7FFFu + ((v.u >> 16) & 1u);
  return (unsigned short)(r >> 16);
}
static __device__ __forceinline__ float bf2f(unsigned short h) {
  union { unsigned int u; float f; } v; v.u = ((unsigned int)h) << 16;
  return v.f;
}
static __device__ __forceinline__ f32x4 mfma16(short8 a, short8 b, f32x4 c) {
  return __builtin_amdgcn_mfma_f32_16x16x32_bf16(a, b, c, 0, 0, 0);
}

// ---------------- GEMM: Y = X @ W + bias  (M=6144, N=512, K=512) ----------------
// IMODE: 0 = f32 flat input, 1 = bf16 head-layout input.
// OMODE: 0 = f32 flat, 2 = bf16 hi/lo head-layout, 3 = bf16 transposed vhT.
template <int IMODE, int OMODE>
__global__ __launch_bounds__(256) void gemm512(const float* __restrict__ X,
                                               const unsigned short* __restrict__ Xb,
                                               const float* __restrict__ W,
                                               const float* __restrict__ bias,
                                               float* __restrict__ Yf,
                                               unsigned short* __restrict__ Yhi,
                                               unsigned short* __restrict__ Ylo) {
  __shared__ float As[16][68];
  __shared__ float Bs[16][64];
  const int m0 = blockIdx.x * 64;
  const int n0 = blockIdx.y * 64;
  const int t  = threadIdx.x;
  const int tx = t & 15, ty = t >> 4;
  float acc[4][4] = {};
  for (int k0 = 0; k0 < 512; k0 += 16) {
#pragma unroll
    for (int u = 0; u < 4; ++u) {
      int idx = t + u * 256;
      int kk = idx & 15, mm = idx >> 4;
      int r = m0 + mm, k = k0 + kk;
      if (IMODE == 1) {
        int bb = r / S, s = r - bb * S;
        size_t xaddr = ((size_t)(bb * H + (k >> 6)) * S + s) * D + (k & 63);
        As[kk][mm] = bf2f(Xb[xaddr]);
      } else {
        As[kk][mm] = X[(size_t)r * 512 + k];
      }
    }
#pragma unroll
    for (int u = 0; u < 4; ++u) {
      int idx = t + u * 256;
      int nn = idx & 63, kk = idx >> 6;
      Bs[kk][nn] = W[(size_t)(k0 + kk) * 512 + n0 + nn];
    }
    __syncthreads();
#pragma unroll
    for (int kk = 0; kk < 16; ++kk) {
      float4 a4 = *(float4*)&As[kk][ty * 4];
      float4 b4 = *(float4*)&Bs[kk][tx * 4];
      float a[4] = {a4.x, a4.y, a4.z, a4.w};
      float bb[4] = {b4.x, b4.y, b4.z, b4.w};
#pragma unroll
      for (int i = 0; i < 4; ++i)
#pragma unroll
        for (int j = 0; j < 4; ++j) acc[i][j] += a[i] * bb[j];
    }
    __syncthreads();
  }
  const int c0 = n0 + tx * 4;
  float4 bi = *(const float4*)&bias[c0];
  float bia[4] = {bi.x, bi.y, bi.z, bi.w};
  if (OMODE == 3) {
    // transposed bf16 write into vhT[(bh*D+d)*S + s]
    const int bb = m0 / S;
    const int s0 = m0 + ty * 4 - bb * S;
    const int h = c0 >> 6;
#pragma unroll
    for (int j = 0; j < 4; ++j) {
      const int d = (c0 & 63) + j;
      ushort4 pk;
      pk.x = f2bf(acc[0][j] + bia[j]);
      pk.y = f2bf(acc[1][j] + bia[j]);
      pk.z = f2bf(acc[2][j] + bia[j]);
      pk.w = f2bf(acc[3][j] + bia[j]);
      *(ushort4*)&Yhi[((size_t)(bb * H + h) * D + d) * S + s0] = pk;
    }
    return;
  }
#pragma unroll
  for (int i = 0; i < 4; ++i) {
    int r = m0 + ty * 4 + i;
    float o[4];
#pragma unroll
    for (int j = 0; j < 4; ++j) o[j] = acc[i][j] + bia[j];
    if (OMODE == 0) {
      *(float4*)&Yf[(size_t)r * 512 + c0] = make_float4(o[0], o[1], o[2], o[3]);
    } else {  // OMODE 2
      int bb = r / S, s = r - bb * S;
      size_t addr = ((size_t)(bb * H + (c0 >> 6)) * S + s) * D + (c0 & 63);
      unsigned short hh[4];
#pragma unroll
      for (int j = 0; j < 4; ++j) hh[j] = f2bf(o[j]);
      uint2 hp = make_uint2((unsigned)hh[0] | ((unsigned)hh[1] << 16),
                            (unsigned)hh[2] | ((unsigned)hh[3] << 16));
      *(uint2*)&Yhi[addr] = hp;
      unsigned short ll[4];
#pragma unroll
      for (int j = 0; j < 4; ++j) ll[j] = f2bf(o[j] - bf2f(hh[j]));
      uint2 lp = make_uint2((unsigned)ll[0] | ((unsigned)ll[1] << 16),
                            (unsigned)ll[2] | ((unsigned)ll[3] << 16));
      *(uint2*)&Ylo[addr] = lp;
    }
  }
}

// ---------------- fused attention: score + bias + softmax + md + att_map + PV ----
// grid (24 row-tiles of 32, 64 bh); block 512 = 8 waves; wave w owns cols [w*96, w*96+96)
__global__ __launch_bounds__(512) void fused_attn(
    const unsigned short* __restrict__ qh_hi, const unsigned short* __restrict__ qh_lo,
    const unsigned short* __restrict__ kh_hi, const unsigned short* __restrict__ kh_lo,
    const unsigned short* __restrict__ vhT,
    const float* __restrict__ mask, const float* __restrict__ depth_value,
    const float* __restrict__ mean_depth,
    float* __restrict__ att_score, float* __restrict__ att_map,
    unsigned short* __restrict__ ctx, float* __restrict__ md_rows)
{
  __shared__ unsigned short Ps[32][776];   // XOR-swizzled bf16 P tile
  __shared__ float pmax[32][8];            // reused: main max -> AV max
  __shared__ float psum[32][8];            // reused: main se  -> AV se
  __shared__ float psem[32][8];            // reused: main sem -> AV sem
  __shared__ float asmd[32][4];
  __shared__ float mxA[32], rdA[32], drefsA[32], mrwA[32];

  const int rt = blockIdx.x, bh = blockIdx.y;
  const int b = bh >> 3, b0 = b >> 2;
  const int r0 = rt * 32;
  const int t = threadIdx.x;
  const int w = t >> 6;
  const int lane = t & 63;
  const int l15 = lane & 15, g = lane >> 4;
  const bool avblk = (r0 >= V);

  if (t < 32) {
    const int row = r0 + t;
    drefsA[t] = (row < V) ? depth_value[(size_t)b0 * V + row]
                          : mean_depth[(size_t)b * A + (row - V)];
    mrwA[t] = mask[(size_t)b * S + row];
  }

  // ---- Q fragments (hi/lo), rows r0..r0+31 ----
  short8 qhi[2][2], qlo[2][2];
#pragma unroll
  for (int tm = 0; tm < 2; ++tm)
#pragma unroll
    for (int ks = 0; ks < 2; ++ks) {
      const size_t a = ((size_t)bh * S + r0 + tm * 16 + l15) * D + ks * 32 + g * 8;
      qhi[tm][ks] = *(const short8*)&qh_hi[a];
      qlo[tm][ks] = *(const short8*)&qh_lo[a];
    }

  // ---- scores: acc[tm][tn] = Q . K^T (split bf16, ~f32 exact) ----
  f32x4 acc[2][6] = {};
#pragma unroll
  for (int tn = 0; tn < 6; ++tn) {
    const int col = w * 96 + tn * 16 + l15;
#pragma unroll
    for (int ks = 0; ks < 2; ++ks) {
      const size_t a = ((size_t)bh * S + col) * D + ks * 32 + g * 8;
      short8 khi = *(const short8*)&kh_hi[a];
      short8 klo = *(const short8*)&kh_lo[a];
#pragma unroll
      for (int tm = 0; tm < 2; ++tm) {
        acc[tm][tn] = mfma16(qlo[tm][ks], khi, acc[tm][tn]);
        acc[tm][tn] = mfma16(qhi[tm][ks], klo, acc[tm][tn]);
        acc[tm][tn] = mfma16(qhi[tm][ks], khi, acc[tm][tn]);
      }
    }
  }
  __syncthreads();  // drefsA/mrwA ready

  // ---- epilogue: scale + depth bias + mask; write att_score; keep x in regs ----
  const float* mb = &mask[(size_t)b * S];
  float mcr[6], dvc[6];
#pragma unroll
  for (int tn = 0; tn < 6; ++tn) {
    const int col = w * 96 + tn * 16 + l15;
    mcr[tn] = mb[col];
    dvc[tn] = (w < 4) ? depth_value[(size_t)b0 * V + col] : 0.f;
  }
#pragma unroll
  for (int tm = 0; tm < 2; ++tm)
#pragma unroll
    for (int r = 0; r < 4; ++r) {
      const int lrow = tm * 16 + g * 4 + r;
      const int row = r0 + lrow;
      const float mr = mrwA[lrow];
      const float dref = drefsA[lrow];
      float* srow = &att_score[((size_t)bh * S + row) * S];
#pragma unroll
      for (int tn = 0; tn < 6; ++tn) {
        const int col = w * 96 + tn * 16 + l15;
        float x = acc[tm][tn][r] * SCALE;
        if (w < 4) {
          float gg = __expf(-fabsf(dref - dvc[tn])) - BBC;
          float bb = fabsf(x) * gg;
          if (row == col) bb = 0.f;
          x += bb;
        }
        x = (mr * mcr[tn] > 0.f) ? x : NEGV;
        srow[col] = x;
        acc[tm][tn][r] = x;
      }
    }

  // ---- main softmax: per-wave row-max partials ----
#pragma unroll
  for (int tm = 0; tm < 2; ++tm)
#pragma unroll
    for (int r = 0; r < 4; ++r) {
      float v = NEGV;
#pragma unroll
      for (int tn = 0; tn < 6; ++tn) v = fmaxf(v, acc[tm][tn][r]);
#pragma unroll
      for (int o = 1; o < 16; o <<= 1) v = fmaxf(v, __shfl_xor(v, o, 16));
      if (l15 == 0) pmax[tm * 16 + g * 4 + r][w] = v;
    }
  __syncthreads();
  if (t < 32) {
    float m = pmax[t][0];
#pragma unroll
    for (int u = 1; u < 8; ++u) m = fmaxf(m, pmax[t][u]);
    mxA[t] = m;
  }
  __syncthreads();

  // ---- AV (pre-bias) softmax + md partials: rows >= V, cols < V ----
  if (avblk) {
    if (w < 4) {
#pragma unroll
      for (int tm = 0; tm < 2; ++tm)
#pragma unroll
        for (int r = 0; r < 4; ++r) {
          const int lrow = tm * 16 + g * 4 + r;
          const float mdv = drefsA[lrow];
          const float mr = mrwA[lrow];
          float v = NEGV;
#pragma unroll
          for (int tn = 0; tn < 6; ++tn) {
            float post = acc[tm][tn][r];
            float gg = __expf(-fabsf(mdv - dvc[tn])) - BBC;
            float pre = post / (post > 0.f ? 1.f + gg : 1.f - gg);
            pre = (mr * mcr[tn] > 0.f) ? pre : NEGV;
            v = fmaxf(v, pre);
          }
#pragma unroll
          for (int o = 1; o < 16; o <<= 1) v = fmaxf(v, __shfl_xor(v, o, 16));
          if (l15 == 0) pmax[lrow][w] = v;
        }
    }
    __syncthreads();
    if (t < 32) {
      float m = fmaxf(fmaxf(pmax[t][0], pmax[t][1]), fmaxf(pmax[t][2], pmax[t][3]));
      rdA[t] = m;  // AV max parked in rdA
    }
    __syncthreads();
    if (w < 4) {
#pragma unroll
      for (int tm = 0; tm < 2; ++tm)
#pragma unroll
        for (int r = 0; r < 4; ++r) {
          const int lrow = tm * 16 + g * 4 + r;
          const float mdv = drefsA[lrow];
          const float mr = mrwA[lrow];
          const float amx = rdA[lrow];
          float se = 0.f, sem = 0.f, smd = 0.f;
#pragma unroll
          for (int tn = 0; tn < 6; ++tn) {
            float post = acc[tm][tn][r];
            float gg = __expf(-fabsf(mdv - dvc[tn])) - BBC;
            float pre = post / (post > 0.f ? 1.f + gg : 1.f - gg);
            float pm = mr * mcr[tn];
            pre = (pm > 0.f) ? pre : NEGV;
            float e = __expf(pre - amx);
            se += e; sem += e * pm; smd += e * pm * dvc[tn];
          }
#pragma unroll
          for (int o = 1; o < 16; o <<= 1) {
            se += __shfl_xor(se, o, 16);
            sem += __shfl_xor(sem, o, 16);
            smd += __shfl_xor(smd, o, 16);
          }
          if (l15 == 0) { psum[lrow][w] = se; psem[lrow][w] = sem; asmd[lrow][w] = smd; }
        }
    }
    __syncthreads();
    if (t < 32) {
      float se = psum[t][0] + psum[t][1] + psum[t][2] + psum[t][3];
      float sem = psem[t][0] + psem[t][1] + psem[t][2] + psem[t][3];
      float smd = asmd[t][0] + asmd[t][1] + asmd[t][2] + asmd[t][3];
      md_rows[(size_t)bh * A + (r0 + t - V)] = smd / (sem + 1e-13f * se);
    }
    __syncthreads();  // before psum/psem reuse
  }

  // ---- main softmax sums (e overwrites x in regs) ----
#pragma unroll
  for (int tm = 0; tm < 2; ++tm)
#pragma unroll
    for (int r = 0; r < 4; ++r) {
      const int lrow = tm * 16 + g * 4 + r;
      const float mx = mxA[lrow];
      const float mr = mrwA[lrow];
      float se = 0.f, sem = 0.f;
#pragma unroll
      for (int tn = 0; tn < 6; ++tn) {
        float e = __expf(acc[tm][tn][r] - mx);
        acc[tm][tn][r] = e;
        se += e; sem += e * (mr * mcr[tn]);
      }
#pragma unroll
      for (int o = 1; o < 16; o <<= 1) {
        se += __shfl_xor(se, o, 16);
        sem += __shfl_xor(sem, o, 16);
      }
      if (l15 == 0) { psum[lrow][w] = se; psem[lrow][w] = sem; }
    }
  __syncthreads();
  if (t < 32) {
    float se = 0.f, sem = 0.f;
#pragma unroll
    for (int u = 0; u < 8; ++u) { se += psum[t][u]; sem += psem[t][u]; }
    rdA[t] = 1.f / (sem + 1e-13f * se);
  }
  __syncthreads();

  // ---- p = e * m * rden: write att_map + swizzled bf16 P ----
#pragma unroll
  for (int tm = 0; tm < 2; ++tm)
#pragma unroll
    for (int r = 0; r < 4; ++r) {
      const int lrow = tm * 16 + g * 4 + r;
      const int row = r0 + lrow;
      const float rden = rdA[lrow];
      const float mr = mrwA[lrow];
      float* prow = &att_map[((size_t)bh * S + row) * S];
      const int swz = (lrow & 7) << 4;
#pragma unroll
      for (int tn = 0; tn < 6; ++tn) {
        const int col = w * 96 + tn * 16 + l15;
        float p = acc[tm][tn][r] * (mr * mcr[tn]) * rden;
        prow[col] = p;
        Ps[lrow][col ^ swz] = f2bf(p);
      }
    }
  __syncthreads();

  // ---- PV: ctx(32x64) = P(32x768) @ V(768x64), wave = (ptm, ptn) ----
  {
    const int ptm = w >> 2, ptn = w & 3;
    const int arow = ptm * 16 + l15;
    const int aswz = (arow & 7) << 4;
    f32x4 pacc = {};
    const unsigned short* vcol = &vhT[((size_t)bh * D + ptn * 16 + l15) * S];
#pragma unroll 8
    for (int kk = 0; kk < 24; ++kk) {
      short8 a = *(short8*)&Ps[arow][(kk * 32 + g * 8) ^ aswz];
      short8 bv = *(const short8*)&vcol[kk * 32 + g * 8];
      pacc = mfma16(a, bv, pacc);
    }
#pragma unroll
    for (int r = 0; r < 4; ++r) {
      const int row = r0 + ptm * 16 + g * 4 + r;
      ctx[((size_t)bh * S + row) * D + ptn * 16 + l15] = f2bf(pacc[r]);
    }
  }
}

// ---------------- md finalize ----------------
__global__ __launch_bounds__(256) void md_finalize(const float* __restrict__ md_rows,
                                                   const float* __restrict__ va_a_mask,
                                                   float* __restrict__ md_out) {
  __shared__ float red0[256];
  __shared__ float red1[256];
  const int b = blockIdx.x;
  const int t = threadIdx.x;
  float s1 = 0.f, s2 = 0.f;
  for (int u = t; u < H * A; u += 256) s1 += md_rows[(size_t)b * H * A + u];
  for (int u = t; u < A; u += 256) s2 += va_a_mask[(size_t)b * A + u];
  red0[t] = s1; red1[t] = s2;
  __syncthreads();
  for (int o = 128; o > 0; o >>= 1) {
    if (t < o) { red0[t] += red0[t + o]; red1[t] += red1[t + o]; }
    __syncthreads();
  }
  const float val = red0[0] / ((float)H * red1[0]);
  for (int u = t; u < A; u += 256) md_out[(size_t)b * A + u] = val;
}

extern "C" void kernel_launch(void* const* d_in, const int* in_sizes, int n_in,
                              void* d_out, int out_size, void* d_ws, size_t ws_size,
                              hipStream_t stream) {
  const float* q           = (const float*)d_in[0];
  const float* k           = (const float*)d_in[1];
  const float* v           = (const float*)d_in[2];
  const float* mask        = (const float*)d_in[3];
  const float* depth_value = (const float*)d_in[4];
  const float* va_a_mask   = (const float*)d_in[7];
  const float* mean_depth  = (const float*)d_in[8];
  const float* Wq = (const float*)d_in[9];
  const float* bq = (const float*)d_in[10];
  const float* Wk = (const float*)d_in[11];
  const float* bk = (const float*)d_in[12];
  const float* Wv = (const float*)d_in[13];
  const float* bv = (const float*)d_in[14];
  const float* Wo = (const float*)d_in[15];
  const float* bo = (const float*)d_in[16];

  unsigned short* wsu = (unsigned short*)d_ws;
  unsigned short* qh_hi = wsu;
  unsigned short* qh_lo = wsu + N_QH;
  unsigned short* kh_hi = wsu + 2 * N_QH;
  unsigned short* kh_lo = wsu + 3 * N_QH;
  unsigned short* vhT   = wsu + 4 * N_QH;
  unsigned short* ctx   = wsu + 5 * N_QH;
  float* md_rows = (float*)(wsu + 6 * N_QH);   // B*H*A f32

  float* out       = (float*)d_out;
  float* att_score = out + (size_t)B * S * HD;
  float* att_map   = att_score + (size_t)B * H * S * S;
  float* md_out    = att_map + (size_t)B * H * S * S;

  dim3 gg(96, 8);
  gemm512<0, 2><<<gg, 256, 0, stream>>>(q, nullptr, Wq, bq, nullptr, qh_hi, qh_lo);
  gemm512<0, 2><<<gg, 256, 0, stream>>>(k, nullptr, Wk, bk, nullptr, kh_hi, kh_lo);
  gemm512<0, 3><<<gg, 256, 0, stream>>>(v, nullptr, Wv, bv, nullptr, vhT, nullptr);
  fused_attn<<<dim3(24, 64), 512, 0, stream>>>(qh_hi, qh_lo, kh_hi, kh_lo, vhT, mask,
                                               depth_value, mean_depth, att_score,
                                               att_map, ctx, md_rows);
  gemm512<1, 0><<<gg, 256, 0, stream>>>(nullptr, ctx, Wo, bo, out, nullptr, nullptr);
  md_finalize<<<B, 256, 0, stream>>>(md_rows, va_a_mask, md_out);
}

// Round 5
// 289.784 us; speedup vs baseline: 2.9172x; 1.2441x over previous
//
#include <hip/hip_runtime.h>
#include <hip/hip_bf16.h>
#include <cstdint>
#include <cstddef>

namespace {
constexpr int B  = 8;
constexpr int S  = 768;
constexpr int V  = 384;
constexpr int A  = 384;
constexpr int H  = 8;
constexpr int D  = 64;
constexpr int HD = 512;
constexpr float SCALE = 0.125f;       // d^-0.5, d=64
constexpr float BBC   = 0.6f;
constexpr float NEGV  = -1000000000.0f;
constexpr size_t N_QH = (size_t)B * H * S * D;   // 3145728
}

using short8 = __attribute__((ext_vector_type(8))) short;
using f32x4  = __attribute__((ext_vector_type(4))) float;

static __device__ __forceinline__ unsigned short f2bf(float f) {
  union { float f; unsigned int u; } v; v.f = f;
  unsigned int r = v.u + 0x7FFFu + ((v.u >> 16) & 1u);
  return (unsigned short)(r >> 16);
}
static __device__ __forceinline__ float bf2f(unsigned short h) {
  union { unsigned int u; float f; } v; v.u = ((unsigned int)h) << 16;
  return v.f;
}
static __device__ __forceinline__ f32x4 mfma16(short8 a, short8 b, f32x4 c) {
  return __builtin_amdgcn_mfma_f32_16x16x32_bf16(a, b, c, 0, 0, 0);
}

// ---------------- prep_w: W[k][n] f32 -> WT hi/lo bf16 [n][k] (truncation split) ----
__global__ __launch_bounds__(256) void prep_w(const float* __restrict__ W0,
                                              const float* __restrict__ W1,
                                              const float* __restrict__ W2,
                                              const float* __restrict__ W3,
                                              unsigned short* __restrict__ wt) {
  __shared__ float tile[64][68];
  const int k0 = blockIdx.x * 64, n0 = blockIdx.y * 64, z = blockIdx.z;
  const float* W = (z == 0) ? W0 : (z == 1) ? W1 : (z == 2) ? W2 : W3;
  unsigned short* WTh = wt + (size_t)z * 524288;
  unsigned short* WTl = WTh + 262144;
  const int t = threadIdx.x;
#pragma unroll
  for (int u = 0; u < 4; ++u) {
    int idx = u * 256 + t;
    int r = idx >> 4, c4 = (idx & 15) * 4;
    *(float4*)&tile[r][c4] = *(const float4*)&W[(size_t)(k0 + r) * 512 + n0 + c4];
  }
  __syncthreads();
#pragma unroll
  for (int u = 0; u < 4; ++u) {
    int idx = u * 256 + t;
    int n = idx >> 4, kq = (idx & 15) * 4;
    unsigned int uh[4], ul[4];
#pragma unroll
    for (int j = 0; j < 4; ++j) {
      float x = tile[kq + j][n];
      unsigned int ux = __float_as_uint(x);
      uh[j] = ux >> 16;
      float r = x - __uint_as_float(ux & 0xFFFF0000u);
      ul[j] = __float_as_uint(r) >> 16;
    }
    uint2 hp = make_uint2(uh[0] | (uh[1] << 16), uh[2] | (uh[3] << 16));
    uint2 lp = make_uint2(ul[0] | (ul[1] << 16), ul[2] | (ul[3] << 16));
    *(uint2*)&WTh[(size_t)(n0 + n) * 512 + k0 + kq] = hp;
    *(uint2*)&WTl[(size_t)(n0 + n) * 512 + k0 + kq] = lp;
  }
}

// ---------------- MFMA GEMM: Y = X @ W + bias (M=6144, N=512, K=512) ----------------
// IMODE: 0 = f32 flat X (split hi/lo on the fly), 1 = bf16 head-layout X (single).
// OMODE: 0 = f32 flat, 2 = bf16 hi/lo head-layout, 3 = bf16 transposed vhT (swapped ops).
template <int IMODE, int OMODE>
__global__ __launch_bounds__(256) void gemm512_mfma(
    const float* __restrict__ X, const unsigned short* __restrict__ Xb,
    const unsigned short* __restrict__ WTh, const unsigned short* __restrict__ WTl,
    const float* __restrict__ bias,
    float* __restrict__ Yf, unsigned short* __restrict__ Yhi,
    unsigned short* __restrict__ Ylo)
{
  __shared__ unsigned short Ah[64][40];
  __shared__ unsigned short Al_[64][40];
  __shared__ unsigned short Bh[64][40];
  __shared__ unsigned short Bl[64][40];
  const int m0 = blockIdx.x * 64, n0 = blockIdx.y * 64;
  const int t = threadIdx.x, w = t >> 6, lane = t & 63;
  const int l15 = lane & 15, g = lane >> 4;
  const int bb = m0 / S;
  f32x4 acc[4] = {};

  for (int k0 = 0; k0 < 512; k0 += 32) {
    __syncthreads();
    if constexpr (IMODE == 0) {
#pragma unroll
      for (int u = 0; u < 2; ++u) {
        int idx = u * 256 + t;
        int row = idx >> 3, kq = (idx & 7) * 4;
        float4 xv = *(const float4*)&X[(size_t)(m0 + row) * 512 + k0 + kq];
        unsigned int u0 = __float_as_uint(xv.x), u1 = __float_as_uint(xv.y);
        unsigned int u2 = __float_as_uint(xv.z), u3 = __float_as_uint(xv.w);
        float r0 = xv.x - __uint_as_float(u0 & 0xFFFF0000u);
        float r1 = xv.y - __uint_as_float(u1 & 0xFFFF0000u);
        float r2 = xv.z - __uint_as_float(u2 & 0xFFFF0000u);
        float r3 = xv.w - __uint_as_float(u3 & 0xFFFF0000u);
        uint2 hp = make_uint2((u1 & 0xFFFF0000u) | (u0 >> 16),
                              (u3 & 0xFFFF0000u) | (u2 >> 16));
        uint2 lp = make_uint2((__float_as_uint(r1) & 0xFFFF0000u) | (__float_as_uint(r0) >> 16),
                              (__float_as_uint(r3) & 0xFFFF0000u) | (__float_as_uint(r2) >> 16));
        *(uint2*)&Ah[row][kq] = hp;
        *(uint2*)&Al_[row][kq] = lp;
      }
    } else {
      int row = t >> 2, kq = (t & 3) * 8;
      int gr = m0 + row;
      int s = gr - bb * S;
      int h = k0 >> 6, d = (k0 & 63) + kq;
      short8 xv = *(const short8*)&Xb[((size_t)(bb * H + h) * S + s) * D + d];
      *(short8*)&Ah[row][kq] = xv;
    }
    {
      int row = t >> 2, kq = (t & 3) * 8;
      *(short8*)&Bh[row][kq] = *(const short8*)&WTh[(size_t)(n0 + row) * 512 + k0 + kq];
      *(short8*)&Bl[row][kq] = *(const short8*)&WTl[(size_t)(n0 + row) * 512 + k0 + kq];
    }
    __syncthreads();
    if constexpr (OMODE != 3) {
      short8 ah = *(short8*)&Ah[w * 16 + l15][g * 8];
      short8 al{};
      if constexpr (IMODE == 0) al = *(short8*)&Al_[w * 16 + l15][g * 8];
#pragma unroll
      for (int tn = 0; tn < 4; ++tn) {
        short8 bh_ = *(short8*)&Bh[tn * 16 + l15][g * 8];
        short8 bl_ = *(short8*)&Bl[tn * 16 + l15][g * 8];
        if constexpr (IMODE == 0) acc[tn] = mfma16(al, bh_, acc[tn]);
        acc[tn] = mfma16(ah, bl_, acc[tn]);
        acc[tn] = mfma16(ah, bh_, acc[tn]);
      }
    } else {
      short8 ah = *(short8*)&Bh[w * 16 + l15][g * 8];
      short8 al = *(short8*)&Bl[w * 16 + l15][g * 8];
#pragma unroll
      for (int tm = 0; tm < 4; ++tm) {
        short8 bh_ = *(short8*)&Ah[tm * 16 + l15][g * 8];
        short8 bl_ = *(short8*)&Al_[tm * 16 + l15][g * 8];
        acc[tm] = mfma16(al, bh_, acc[tm]);
        acc[tm] = mfma16(ah, bl_, acc[tm]);
        acc[tm] = mfma16(ah, bh_, acc[tm]);
      }
    }
  }

  if constexpr (OMODE == 0) {
#pragma unroll
    for (int tn = 0; tn < 4; ++tn) {
      const int c = n0 + tn * 16 + l15;
      const float bi = bias[c];
#pragma unroll
      for (int r = 0; r < 4; ++r) {
        const int m = m0 + w * 16 + g * 4 + r;
        Yf[(size_t)m * 512 + c] = acc[tn][r] + bi;
      }
    }
  } else if constexpr (OMODE == 2) {
#pragma unroll
    for (int tn = 0; tn < 4; ++tn) {
      const int c = n0 + tn * 16 + l15;
      const float bi = bias[c];
      const int h = c >> 6, d = c & 63;
#pragma unroll
      for (int r = 0; r < 4; ++r) {
        const int m = m0 + w * 16 + g * 4 + r;
        const int s = m - bb * S;
        const size_t addr = ((size_t)(bb * H + h) * S + s) * D + d;
        float o = acc[tn][r] + bi;
        unsigned int uo = __float_as_uint(o);
        unsigned short hh = (unsigned short)(uo >> 16);
        float rr = o - __uint_as_float(uo & 0xFFFF0000u);
        Yhi[addr] = hh;
        Ylo[addr] = (unsigned short)(__float_as_uint(rr) >> 16);
      }
    }
  } else {  // OMODE == 3: D[n][m], lanes along s -> coalesced vhT stores
#pragma unroll
    for (int tm = 0; tm < 4; ++tm) {
      const int mcol = m0 + tm * 16 + l15;
      const int s = mcol - bb * S;
#pragma unroll
      for (int r = 0; r < 4; ++r) {
        const int n = n0 + w * 16 + g * 4 + r;
        const int h = n >> 6, d = n & 63;
        float o = acc[tm][r] + bias[n];
        Yhi[((size_t)(bb * H + h) * D + d) * S + s] = f2bf(o);
      }
    }
  }
}

// ---------------- fused attention: score + bias + softmax + md + att_map + PV ----
// grid (24 row-tiles of 32, 64 bh); block 512 = 8 waves; wave w owns cols [w*96, w*96+96)
__global__ __launch_bounds__(512) void fused_attn(
    const unsigned short* __restrict__ qh_hi, const unsigned short* __restrict__ qh_lo,
    const unsigned short* __restrict__ kh_hi, const unsigned short* __restrict__ kh_lo,
    const unsigned short* __restrict__ vhT,
    const float* __restrict__ mask, const float* __restrict__ depth_value,
    const float* __restrict__ mean_depth,
    float* __restrict__ att_score, float* __restrict__ att_map,
    unsigned short* __restrict__ ctx, float* __restrict__ md_rows)
{
  __shared__ unsigned short Ps[32][776];   // XOR-swizzled bf16 P tile
  __shared__ float pmax[32][8];
  __shared__ float psum[32][8];
  __shared__ float psem[32][8];
  __shared__ float asmd[32][4];
  __shared__ float mxA[32], rdA[32], drefsA[32], mrwA[32];

  const int rt = blockIdx.x, bh = blockIdx.y;
  const int b = bh >> 3, b0 = b >> 2;
  const int r0 = rt * 32;
  const int t = threadIdx.x;
  const int w = t >> 6;
  const int lane = t & 63;
  const int l15 = lane & 15, g = lane >> 4;
  const bool avblk = (r0 >= V);

  if (t < 32) {
    const int row = r0 + t;
    drefsA[t] = (row < V) ? depth_value[(size_t)b0 * V + row]
                          : mean_depth[(size_t)b * A + (row - V)];
    mrwA[t] = mask[(size_t)b * S + row];
  }

  short8 qhi[2][2], qlo[2][2];
#pragma unroll
  for (int tm = 0; tm < 2; ++tm)
#pragma unroll
    for (int ks = 0; ks < 2; ++ks) {
      const size_t a = ((size_t)bh * S + r0 + tm * 16 + l15) * D + ks * 32 + g * 8;
      qhi[tm][ks] = *(const short8*)&qh_hi[a];
      qlo[tm][ks] = *(const short8*)&qh_lo[a];
    }

  f32x4 acc[2][6] = {};
#pragma unroll
  for (int tn = 0; tn < 6; ++tn) {
    const int col = w * 96 + tn * 16 + l15;
#pragma unroll
    for (int ks = 0; ks < 2; ++ks) {
      const size_t a = ((size_t)bh * S + col) * D + ks * 32 + g * 8;
      short8 khi = *(const short8*)&kh_hi[a];
      short8 klo = *(const short8*)&kh_lo[a];
#pragma unroll
      for (int tm = 0; tm < 2; ++tm) {
        acc[tm][tn] = mfma16(qlo[tm][ks], khi, acc[tm][tn]);
        acc[tm][tn] = mfma16(qhi[tm][ks], klo, acc[tm][tn]);
        acc[tm][tn] = mfma16(qhi[tm][ks], khi, acc[tm][tn]);
      }
    }
  }
  __syncthreads();

  const float* mb = &mask[(size_t)b * S];
  float mcr[6], dvc[6];
#pragma unroll
  for (int tn = 0; tn < 6; ++tn) {
    const int col = w * 96 + tn * 16 + l15;
    mcr[tn] = mb[col];
    dvc[tn] = (w < 4) ? depth_value[(size_t)b0 * V + col] : 0.f;
  }
#pragma unroll
  for (int tm = 0; tm < 2; ++tm)
#pragma unroll
    for (int r = 0; r < 4; ++r) {
      const int lrow = tm * 16 + g * 4 + r;
      const int row = r0 + lrow;
      const float mr = mrwA[lrow];
      const float dref = drefsA[lrow];
      float* srow = &att_score[((size_t)bh * S + row) * S];
#pragma unroll
      for (int tn = 0; tn < 6; ++tn) {
        const int col = w * 96 + tn * 16 + l15;
        float x = acc[tm][tn][r] * SCALE;
        if (w < 4) {
          float gg = __expf(-fabsf(dref - dvc[tn])) - BBC;
          float bb2 = fabsf(x) * gg;
          if (row == col) bb2 = 0.f;
          x += bb2;
        }
        x = (mr * mcr[tn] > 0.f) ? x : NEGV;
        srow[col] = x;
        acc[tm][tn][r] = x;
      }
    }

#pragma unroll
  for (int tm = 0; tm < 2; ++tm)
#pragma unroll
    for (int r = 0; r < 4; ++r) {
      float v = NEGV;
#pragma unroll
      for (int tn = 0; tn < 6; ++tn) v = fmaxf(v, acc[tm][tn][r]);
#pragma unroll
      for (int o = 1; o < 16; o <<= 1) v = fmaxf(v, __shfl_xor(v, o, 16));
      if (l15 == 0) pmax[tm * 16 + g * 4 + r][w] = v;
    }
  __syncthreads();
  if (t < 32) {
    float m = pmax[t][0];
#pragma unroll
    for (int u = 1; u < 8; ++u) m = fmaxf(m, pmax[t][u]);
    mxA[t] = m;
  }
  __syncthreads();

  if (avblk) {
    if (w < 4) {
#pragma unroll
      for (int tm = 0; tm < 2; ++tm)
#pragma unroll
        for (int r = 0; r < 4; ++r) {
          const int lrow = tm * 16 + g * 4 + r;
          const float mdv = drefsA[lrow];
          const float mr = mrwA[lrow];
          float v = NEGV;
#pragma unroll
          for (int tn = 0; tn < 6; ++tn) {
            float post = acc[tm][tn][r];
            float gg = __expf(-fabsf(mdv - dvc[tn])) - BBC;
            float pre = post / (post > 0.f ? 1.f + gg : 1.f - gg);
            pre = (mr * mcr[tn] > 0.f) ? pre : NEGV;
            v = fmaxf(v, pre);
          }
#pragma unroll
          for (int o = 1; o < 16; o <<= 1) v = fmaxf(v, __shfl_xor(v, o, 16));
          if (l15 == 0) pmax[lrow][w] = v;
        }
    }
    __syncthreads();
    if (t < 32) {
      float m = fmaxf(fmaxf(pmax[t][0], pmax[t][1]), fmaxf(pmax[t][2], pmax[t][3]));
      rdA[t] = m;
    }
    __syncthreads();
    if (w < 4) {
#pragma unroll
      for (int tm = 0; tm < 2; ++tm)
#pragma unroll
        for (int r = 0; r < 4; ++r) {
          const int lrow = tm * 16 + g * 4 + r;
          const float mdv = drefsA[lrow];
          const float mr = mrwA[lrow];
          const float amx = rdA[lrow];
          float se = 0.f, sem = 0.f, smd = 0.f;
#pragma unroll
          for (int tn = 0; tn < 6; ++tn) {
            float post = acc[tm][tn][r];
            float gg = __expf(-fabsf(mdv - dvc[tn])) - BBC;
            float pre = post / (post > 0.f ? 1.f + gg : 1.f - gg);
            float pm = mr * mcr[tn];
            pre = (pm > 0.f) ? pre : NEGV;
            float e = __expf(pre - amx);
            se += e; sem += e * pm; smd += e * pm * dvc[tn];
          }
#pragma unroll
          for (int o = 1; o < 16; o <<= 1) {
            se += __shfl_xor(se, o, 16);
            sem += __shfl_xor(sem, o, 16);
            smd += __shfl_xor(smd, o, 16);
          }
          if (l15 == 0) { psum[lrow][w] = se; psem[lrow][w] = sem; asmd[lrow][w] = smd; }
        }
    }
    __syncthreads();
    if (t < 32) {
      float se = psum[t][0] + psum[t][1] + psum[t][2] + psum[t][3];
      float sem = psem[t][0] + psem[t][1] + psem[t][2] + psem[t][3];
      float smd = asmd[t][0] + asmd[t][1] + asmd[t][2] + asmd[t][3];
      md_rows[(size_t)bh * A + (r0 + t - V)] = smd / (sem + 1e-13f * se);
    }
    __syncthreads();
  }

#pragma unroll
  for (int tm = 0; tm < 2; ++tm)
#pragma unroll
    for (int r = 0; r < 4; ++r) {
      const int lrow = tm * 16 + g * 4 + r;
      const float mx = mxA[lrow];
      const float mr = mrwA[lrow];
      float se = 0.f, sem = 0.f;
#pragma unroll
      for (int tn = 0; tn < 6; ++tn) {
        float e = __expf(acc[tm][tn][r] - mx);
        acc[tm][tn][r] = e;
        se += e; sem += e * (mr * mcr[tn]);
      }
#pragma unroll
      for (int o = 1; o < 16; o <<= 1) {
        se += __shfl_xor(se, o, 16);
        sem += __shfl_xor(sem, o, 16);
      }
      if (l15 == 0) { psum[lrow][w] = se; psem[lrow][w] = sem; }
    }
  __syncthreads();
  if (t < 32) {
    float se = 0.f, sem = 0.f;
#pragma unroll
    for (int u = 0; u < 8; ++u) { se += psum[t][u]; sem += psem[t][u]; }
    rdA[t] = 1.f / (sem + 1e-13f * se);
  }
  __syncthreads();

#pragma unroll
  for (int tm = 0; tm < 2; ++tm)
#pragma unroll
    for (int r = 0; r < 4; ++r) {
      const int lrow = tm * 16 + g * 4 + r;
      const int row = r0 + lrow;
      const float rden = rdA[lrow];
      const float mr = mrwA[lrow];
      float* prow = &att_map[((size_t)bh * S + row) * S];
      const int swz = (lrow & 7) << 4;
#pragma unroll
      for (int tn = 0; tn < 6; ++tn) {
        const int col = w * 96 + tn * 16 + l15;
        float p = acc[tm][tn][r] * (mr * mcr[tn]) * rden;
        prow[col] = p;
        Ps[lrow][col ^ swz] = f2bf(p);
      }
    }
  __syncthreads();

  {
    const int ptm = w >> 2, ptn = w & 3;
    const int arow = ptm * 16 + l15;
    const int aswz = (arow & 7) << 4;
    f32x4 pacc = {};
    const unsigned short* vcol = &vhT[((size_t)bh * D + ptn * 16 + l15) * S];
#pragma unroll 8
    for (int kk = 0; kk < 24; ++kk) {
      short8 a = *(short8*)&Ps[arow][(kk * 32 + g * 8) ^ aswz];
      short8 bv = *(const short8*)&vcol[kk * 32 + g * 8];
      pacc = mfma16(a, bv, pacc);
    }
#pragma unroll
    for (int r = 0; r < 4; ++r) {
      const int row = r0 + ptm * 16 + g * 4 + r;
      ctx[((size_t)bh * S + row) * D + ptn * 16 + l15] = f2bf(pacc[r]);
    }
  }
}

// ---------------- md finalize ----------------
__global__ __launch_bounds__(256) void md_finalize(const float* __restrict__ md_rows,
                                                   const float* __restrict__ va_a_mask,
                                                   float* __restrict__ md_out) {
  __shared__ float red0[256];
  __shared__ float red1[256];
  const int b = blockIdx.x;
  const int t = threadIdx.x;
  float s1 = 0.f, s2 = 0.f;
  for (int u = t; u < H * A; u += 256) s1 += md_rows[(size_t)b * H * A + u];
  for (int u = t; u < A; u += 256) s2 += va_a_mask[(size_t)b * A + u];
  red0[t] = s1; red1[t] = s2;
  __syncthreads();
  for (int o = 128; o > 0; o >>= 1) {
    if (t < o) { red0[t] += red0[t + o]; red1[t] += red1[t + o]; }
    __syncthreads();
  }
  const float val = red0[0] / ((float)H * red1[0]);
  for (int u = t; u < A; u += 256) md_out[(size_t)b * A + u] = val;
}

extern "C" void kernel_launch(void* const* d_in, const int* in_sizes, int n_in,
                              void* d_out, int out_size, void* d_ws, size_t ws_size,
                              hipStream_t stream) {
  const float* q           = (const float*)d_in[0];
  const float* k           = (const float*)d_in[1];
  const float* v           = (const float*)d_in[2];
  const float* mask        = (const float*)d_in[3];
  const float* depth_value = (const float*)d_in[4];
  const float* va_a_mask   = (const float*)d_in[7];
  const float* mean_depth  = (const float*)d_in[8];
  const float* Wq = (const float*)d_in[9];
  const float* bq = (const float*)d_in[10];
  const float* Wk = (const float*)d_in[11];
  const float* bk = (const float*)d_in[12];
  const float* Wv = (const float*)d_in[13];
  const float* bv = (const float*)d_in[14];
  const float* Wo = (const float*)d_in[15];
  const float* bo = (const float*)d_in[16];

  unsigned short* wsu = (unsigned short*)d_ws;
  unsigned short* qh_hi = wsu;                 // aliased by ctx after score phase
  unsigned short* qh_lo = wsu + N_QH;
  unsigned short* kh_hi = wsu + 2 * N_QH;
  unsigned short* kh_lo = wsu + 3 * N_QH;
  unsigned short* vhT   = wsu + 4 * N_QH;
  unsigned short* ctx   = qh_hi;               // alias (per-row ownership matches)
  unsigned short* wt    = wsu + 5 * N_QH;      // 4 weights x (hi+lo) x 262144
  float* md_rows = (float*)(wsu + 5 * N_QH + 4 * 524288);

  float* out       = (float*)d_out;
  float* att_score = out + (size_t)B * S * HD;
  float* att_map   = att_score + (size_t)B * H * S * S;
  float* md_out    = att_map + (size_t)B * H * S * S;

  dim3 gg(96, 8);
  prep_w<<<dim3(8, 8, 4), 256, 0, stream>>>(Wq, Wk, Wv, Wo, wt);
  gemm512_mfma<0, 2><<<gg, 256, 0, stream>>>(q, nullptr, wt, wt + 262144, bq,
                                             nullptr, qh_hi, qh_lo);
  gemm512_mfma<0, 2><<<gg, 256, 0, stream>>>(k, nullptr, wt + 524288, wt + 786432, bk,
                                             nullptr, kh_hi, kh_lo);
  gemm512_mfma<0, 3><<<gg, 256, 0, stream>>>(v, nullptr, wt + 1048576, wt + 1310720, bv,
                                             nullptr, vhT, nullptr);
  fused_attn<<<dim3(24, 64), 512, 0, stream>>>(qh_hi, qh_lo, kh_hi, kh_lo, vhT, mask,
                                               depth_value, mean_depth, att_score,
                                               att_map, ctx, md_rows);
  gemm512_mfma<1, 0><<<gg, 256, 0, stream>>>(nullptr, ctx, wt + 1572864, wt + 1835008,
                                             bo, out, nullptr, nullptr);
  md_finalize<<<B, 256, 0, stream>>>(md_rows, va_a_mask, md_out);
}

// Round 6
// 228.041 us; speedup vs baseline: 3.7071x; 1.2708x over previous
//
#include <hip/hip_runtime.h>
#include <hip/hip_bf16.h>
#include <cstdint>
#include <cstddef>

namespace {
constexpr int B  = 8;
constexpr int S  = 768;
constexpr int V  = 384;
constexpr int A  = 384;
constexpr int H  = 8;
constexpr int D  = 64;
constexpr int HD = 512;
constexpr float SCALE = 0.125f;       // d^-0.5, d=64
constexpr float BBC   = 0.6f;
constexpr float NEGV  = -1000000000.0f;
constexpr size_t N_QH = (size_t)B * H * S * D;   // 3145728 (= 6144*512)
}

using short8 = __attribute__((ext_vector_type(8))) short;
using f32x4  = __attribute__((ext_vector_type(4))) float;

static __device__ __forceinline__ unsigned short f2bf(float f) {
  union { float f; unsigned int u; } v; v.f = f;
  unsigned int r = v.u + 0x7FFFu + ((v.u >> 16) & 1u);
  return (unsigned short)(r >> 16);
}
static __device__ __forceinline__ f32x4 mfma16(short8 a, short8 b, f32x4 c) {
  return __builtin_amdgcn_mfma_f32_16x16x32_bf16(a, b, c, 0, 0, 0);
}

// ---------------- prep_all: weights -> WT hi/lo [n][k]; q/k/v -> hi/lo bf16 flat ----
// grid 1D 544: id<256 -> weight tile (z=id>>6, 8x8 tiles); id>=256 -> x split (3x96)
__global__ __launch_bounds__(256) void prep_all(
    const float* __restrict__ Wq, const float* __restrict__ Wk,
    const float* __restrict__ Wv, const float* __restrict__ Wo,
    const float* __restrict__ q, const float* __restrict__ k,
    const float* __restrict__ v,
    unsigned short* __restrict__ wt, unsigned short* __restrict__ xs)
{
  const int id = blockIdx.x;
  const int t = threadIdx.x;
  if (id < 256) {
    __shared__ float tile[64][68];
    const int z = id >> 6, tl = id & 63;
    const int k0 = (tl >> 3) * 64, n0 = (tl & 7) * 64;
    const float* W = (z == 0) ? Wq : (z == 1) ? Wk : (z == 2) ? Wv : Wo;
    unsigned short* WTh = wt + (size_t)z * 524288;
    unsigned short* WTl = WTh + 262144;
#pragma unroll
    for (int u = 0; u < 4; ++u) {
      int idx = u * 256 + t;
      int r = idx >> 4, c4 = (idx & 15) * 4;
      *(float4*)&tile[r][c4] = *(const float4*)&W[(size_t)(k0 + r) * 512 + n0 + c4];
    }
    __syncthreads();
#pragma unroll
    for (int u = 0; u < 4; ++u) {
      int idx = u * 256 + t;
      int n = idx >> 4, kq = (idx & 15) * 4;
      unsigned int uh[4], ul[4];
#pragma unroll
      for (int j = 0; j < 4; ++j) {
        float x = tile[kq + j][n];
        unsigned int ux = __float_as_uint(x);
        uh[j] = ux >> 16;
        float r = x - __uint_as_float(ux & 0xFFFF0000u);
        ul[j] = __float_as_uint(r) >> 16;
      }
      *(uint2*)&WTh[(size_t)(n0 + n) * 512 + k0 + kq] =
          make_uint2(uh[0] | (uh[1] << 16), uh[2] | (uh[3] << 16));
      *(uint2*)&WTl[(size_t)(n0 + n) * 512 + k0 + kq] =
          make_uint2(ul[0] | (ul[1] << 16), ul[2] | (ul[3] << 16));
    }
  } else {
    const int m = id - 256;
    const int z = m / 96, rb = m % 96;
    const float* X = (z == 0) ? q : (z == 1) ? k : v;
    unsigned short* xh = xs + (size_t)z * 2 * N_QH;
    unsigned short* xl = xh + N_QH;
#pragma unroll 4
    for (int u = 0; u < 32; ++u) {
      int idx = u * 256 + t;
      int row = idx >> 7, c = (idx & 127) * 4;
      size_t base = (size_t)(rb * 64 + row) * 512 + c;
      float4 xv = *(const float4*)&X[base];
      unsigned int u0 = __float_as_uint(xv.x), u1 = __float_as_uint(xv.y);
      unsigned int u2 = __float_as_uint(xv.z), u3 = __float_as_uint(xv.w);
      float r0 = xv.x - __uint_as_float(u0 & 0xFFFF0000u);
      float r1 = xv.y - __uint_as_float(u1 & 0xFFFF0000u);
      float r2 = xv.z - __uint_as_float(u2 & 0xFFFF0000u);
      float r3 = xv.w - __uint_as_float(u3 & 0xFFFF0000u);
      *(uint2*)&xh[base] = make_uint2((u1 & 0xFFFF0000u) | (u0 >> 16),
                                      (u3 & 0xFFFF0000u) | (u2 >> 16));
      *(uint2*)&xl[base] = make_uint2(
          (__float_as_uint(r1) & 0xFFFF0000u) | (__float_as_uint(r0) >> 16),
          (__float_as_uint(r3) & 0xFFFF0000u) | (__float_as_uint(r2) >> 16));
    }
  }
}

// ---------------- qkv projections: one launch, z = 0(q)/1(k)/2(v) ----------------
// grid (96, 8, 3); 256 thr = 4 waves; 64x64 tile, K=512, 3-pass split MFMA
__global__ __launch_bounds__(256) void qkv_mfma(
    const unsigned short* __restrict__ xs, const unsigned short* __restrict__ wt,
    const float* __restrict__ bq, const float* __restrict__ bk,
    const float* __restrict__ bv,
    unsigned short* __restrict__ qh_hi, unsigned short* __restrict__ qh_lo,
    unsigned short* __restrict__ kh_hi, unsigned short* __restrict__ kh_lo,
    unsigned short* __restrict__ vhT)
{
  __shared__ unsigned short Ah[64][40];
  __shared__ unsigned short Al_[64][40];
  __shared__ unsigned short Bh[64][40];
  __shared__ unsigned short Bl[64][40];
  const int m0 = blockIdx.x * 64, n0 = blockIdx.y * 64, z = blockIdx.z;
  const unsigned short* Xh = xs + (size_t)z * 2 * N_QH;
  const unsigned short* Xl = Xh + N_QH;
  const unsigned short* WTh = wt + (size_t)z * 524288;
  const unsigned short* WTl = WTh + 262144;
  const float* bias = (z == 0) ? bq : (z == 1) ? bk : bv;
  const int t = threadIdx.x, w = t >> 6, lane = t & 63;
  const int l15 = lane & 15, g = lane >> 4;
  const int bb = m0 / S;
  f32x4 acc[4] = {};

  const int srow = t >> 2, skq = (t & 3) * 8;
  for (int k0 = 0; k0 < 512; k0 += 32) {
    __syncthreads();
    *(short8*)&Ah[srow][skq]  = *(const short8*)&Xh[(size_t)(m0 + srow) * 512 + k0 + skq];
    *(short8*)&Al_[srow][skq] = *(const short8*)&Xl[(size_t)(m0 + srow) * 512 + k0 + skq];
    *(short8*)&Bh[srow][skq]  = *(const short8*)&WTh[(size_t)(n0 + srow) * 512 + k0 + skq];
    *(short8*)&Bl[srow][skq]  = *(const short8*)&WTl[(size_t)(n0 + srow) * 512 + k0 + skq];
    __syncthreads();
    if (z != 2) {
      short8 ah = *(short8*)&Ah[w * 16 + l15][g * 8];
      short8 al = *(short8*)&Al_[w * 16 + l15][g * 8];
#pragma unroll
      for (int tn = 0; tn < 4; ++tn) {
        short8 bh_ = *(short8*)&Bh[tn * 16 + l15][g * 8];
        short8 bl_ = *(short8*)&Bl[tn * 16 + l15][g * 8];
        acc[tn] = mfma16(al, bh_, acc[tn]);
        acc[tn] = mfma16(ah, bl_, acc[tn]);
        acc[tn] = mfma16(ah, bh_, acc[tn]);
      }
    } else {  // swapped operands: D[n][m] -> coalesced vhT stores
      short8 ah = *(short8*)&Bh[w * 16 + l15][g * 8];
      short8 al = *(short8*)&Bl[w * 16 + l15][g * 8];
#pragma unroll
      for (int tm = 0; tm < 4; ++tm) {
        short8 bh_ = *(short8*)&Ah[tm * 16 + l15][g * 8];
        short8 bl_ = *(short8*)&Al_[tm * 16 + l15][g * 8];
        acc[tm] = mfma16(al, bh_, acc[tm]);
        acc[tm] = mfma16(ah, bl_, acc[tm]);
        acc[tm] = mfma16(ah, bh_, acc[tm]);
      }
    }
  }

  if (z != 2) {
    unsigned short* Yhi = (z == 0) ? qh_hi : kh_hi;
    unsigned short* Ylo = (z == 0) ? qh_lo : kh_lo;
#pragma unroll
    for (int tn = 0; tn < 4; ++tn) {
      const int c = n0 + tn * 16 + l15;
      const float bi = bias[c];
      const int h = c >> 6, d = c & 63;
#pragma unroll
      for (int r = 0; r < 4; ++r) {
        const int mm = m0 + w * 16 + g * 4 + r;
        const int s = mm - bb * S;
        const size_t addr = ((size_t)(bb * H + h) * S + s) * D + d;
        float o = acc[tn][r] + bi;
        unsigned int uo = __float_as_uint(o);
        Yhi[addr] = (unsigned short)(uo >> 16);
        float rr = o - __uint_as_float(uo & 0xFFFF0000u);
        Ylo[addr] = (unsigned short)(__float_as_uint(rr) >> 16);
      }
    }
  } else {
#pragma unroll
    for (int tm = 0; tm < 4; ++tm) {
      const int mcol = m0 + tm * 16 + l15;
      const int s = mcol - bb * S;
#pragma unroll
      for (int r = 0; r < 4; ++r) {
        const int n = n0 + w * 16 + g * 4 + r;
        const int h = n >> 6, d = n & 63;
        float o = acc[tm][r] + bias[n];
        vhT[((size_t)(bb * H + h) * D + d) * S + s] = f2bf(o);
      }
    }
  }
}

// ---------------- out projection: out = ctx(bf16 head-layout) @ Wo + bo ----------
__global__ __launch_bounds__(256) void gemm_out(
    const unsigned short* __restrict__ Xb, const unsigned short* __restrict__ WTh,
    const unsigned short* __restrict__ WTl, const float* __restrict__ bias,
    float* __restrict__ Yf)
{
  __shared__ unsigned short Ah[64][40];
  __shared__ unsigned short Bh[64][40];
  __shared__ unsigned short Bl[64][40];
  const int m0 = blockIdx.x * 64, n0 = blockIdx.y * 64;
  const int t = threadIdx.x, w = t >> 6, lane = t & 63;
  const int l15 = lane & 15, g = lane >> 4;
  const int bb = m0 / S;
  f32x4 acc[4] = {};
  const int srow = t >> 2, skq = (t & 3) * 8;
  for (int k0 = 0; k0 < 512; k0 += 32) {
    __syncthreads();
    {
      const int gr = m0 + srow;
      const int s = gr - bb * S;
      const int h = k0 >> 6, d = (k0 & 63) + skq;
      *(short8*)&Ah[srow][skq] = *(const short8*)&Xb[((size_t)(bb * H + h) * S + s) * D + d];
    }
    *(short8*)&Bh[srow][skq] = *(const short8*)&WTh[(size_t)(n0 + srow) * 512 + k0 + skq];
    *(short8*)&Bl[srow][skq] = *(const short8*)&WTl[(size_t)(n0 + srow) * 512 + k0 + skq];
    __syncthreads();
    short8 ah = *(short8*)&Ah[w * 16 + l15][g * 8];
#pragma unroll
    for (int tn = 0; tn < 4; ++tn) {
      short8 bh_ = *(short8*)&Bh[tn * 16 + l15][g * 8];
      short8 bl_ = *(short8*)&Bl[tn * 16 + l15][g * 8];
      acc[tn] = mfma16(ah, bl_, acc[tn]);
      acc[tn] = mfma16(ah, bh_, acc[tn]);
    }
  }
#pragma unroll
  for (int tn = 0; tn < 4; ++tn) {
    const int c = n0 + tn * 16 + l15;
    const float bi = bias[c];
#pragma unroll
    for (int r = 0; r < 4; ++r) {
      const int m = m0 + w * 16 + g * 4 + r;
      Yf[(size_t)m * 512 + c] = acc[tn][r] + bi;
    }
  }
}

// ---------------- fused attention: score + bias + softmax + md + att_map + PV ----
// 1D grid 1536, XCD-swizzled: id = (bh&7) + 8*(rt + 24*(bh>>3))
__global__ __launch_bounds__(512) void fused_attn(
    const unsigned short* __restrict__ qh_hi, const unsigned short* __restrict__ qh_lo,
    const unsigned short* __restrict__ kh_hi, const unsigned short* __restrict__ kh_lo,
    const unsigned short* __restrict__ vhT,
    const float* __restrict__ mask, const float* __restrict__ depth_value,
    const float* __restrict__ mean_depth,
    float* __restrict__ att_score, float* __restrict__ att_map,
    unsigned short* __restrict__ ctx, float* __restrict__ md_rows)
{
  __shared__ unsigned short Ps[32][768];   // XOR-swizzled bf16 P tile
  __shared__ float pmax[32][8];
  __shared__ float psum[32][8];
  __shared__ float psem[32][8];
  __shared__ float asmd[32][4];
  __shared__ float mxA[32], rdA[32], drefsA[32], mrwA[32];

  const int id = blockIdx.x;
  const int rest = id >> 3;
  const int rt = rest % 24;
  const int bh = (id & 7) + 8 * (rest / 24);
  const int b = bh >> 3, b0 = b >> 2;
  const int r0 = rt * 32;
  const int t = threadIdx.x;
  const int w = t >> 6;
  const int lane = t & 63;
  const int l15 = lane & 15, g = lane >> 4;
  const bool avblk = (r0 >= V);

  if (t < 32) {
    const int row = r0 + t;
    drefsA[t] = (row < V) ? depth_value[(size_t)b0 * V + row]
                          : mean_depth[(size_t)b * A + (row - V)];
    mrwA[t] = mask[(size_t)b * S + row];
  }

  short8 qhi[2][2], qlo[2][2];
#pragma unroll
  for (int tm = 0; tm < 2; ++tm)
#pragma unroll
    for (int ks = 0; ks < 2; ++ks) {
      const size_t a = ((size_t)bh * S + r0 + tm * 16 + l15) * D + ks * 32 + g * 8;
      qhi[tm][ks] = *(const short8*)&qh_hi[a];
      qlo[tm][ks] = *(const short8*)&qh_lo[a];
    }

  f32x4 acc[2][6] = {};
#pragma unroll
  for (int tn = 0; tn < 6; ++tn) {
    const int col = w * 96 + tn * 16 + l15;
#pragma unroll
    for (int ks = 0; ks < 2; ++ks) {
      const size_t a = ((size_t)bh * S + col) * D + ks * 32 + g * 8;
      short8 khi = *(const short8*)&kh_hi[a];
      short8 klo = *(const short8*)&kh_lo[a];
#pragma unroll
      for (int tm = 0; tm < 2; ++tm) {
        acc[tm][tn] = mfma16(qlo[tm][ks], khi, acc[tm][tn]);
        acc[tm][tn] = mfma16(qhi[tm][ks], klo, acc[tm][tn]);
        acc[tm][tn] = mfma16(qhi[tm][ks], khi, acc[tm][tn]);
      }
    }
  }
  __syncthreads();

  const float* mb = &mask[(size_t)b * S];
  float mcr[6], dvc[6];
#pragma unroll
  for (int tn = 0; tn < 6; ++tn) {
    const int col = w * 96 + tn * 16 + l15;
    mcr[tn] = mb[col];
    dvc[tn] = (w < 4) ? depth_value[(size_t)b0 * V + col] : 0.f;
  }
#pragma unroll
  for (int tm = 0; tm < 2; ++tm)
#pragma unroll
    for (int r = 0; r < 4; ++r) {
      const int lrow = tm * 16 + g * 4 + r;
      const int row = r0 + lrow;
      const float mr = mrwA[lrow];
      const float dref = drefsA[lrow];
      float* srow = &att_score[((size_t)bh * S + row) * S];
#pragma unroll
      for (int tn = 0; tn < 6; ++tn) {
        const int col = w * 96 + tn * 16 + l15;
        float x = acc[tm][tn][r] * SCALE;
        if (w < 4) {
          float gg = __expf(-fabsf(dref - dvc[tn])) - BBC;
          float bb2 = fabsf(x) * gg;
          if (row == col) bb2 = 0.f;
          x += bb2;
        }
        x = (mr * mcr[tn] > 0.f) ? x : NEGV;
        srow[col] = x;
        acc[tm][tn][r] = x;
      }
    }

  // ---- main row max ----
#pragma unroll
  for (int tm = 0; tm < 2; ++tm)
#pragma unroll
    for (int r = 0; r < 4; ++r) {
      float v = NEGV;
#pragma unroll
      for (int tn = 0; tn < 6; ++tn) v = fmaxf(v, acc[tm][tn][r]);
#pragma unroll
      for (int o = 1; o < 16; o <<= 1) v = fmaxf(v, __shfl_xor(v, o, 16));
      if (l15 == 0) pmax[tm * 16 + g * 4 + r][w] = v;
    }
  __syncthreads();
  if (t < 32) {
    float m = pmax[t][0];
#pragma unroll
    for (int u = 1; u < 8; ++u) m = fmaxf(m, pmax[t][u]);
    mxA[t] = m;
  }
  __syncthreads();

  // ---- AV (pre-bias) softmax + md: single pass, bounded-max trick ----
  // pre = post/(1±g), divisor in (0.4,1.6)  =>  max(pre) <= max(2.5*mx, 0).
  // Uniform exp scaling cancels exactly in md (incl. the 1e-13*se term).
  if (avblk) {
    if (w < 4) {
#pragma unroll
      for (int tm = 0; tm < 2; ++tm)
#pragma unroll
        for (int r = 0; r < 4; ++r) {
          const int lrow = tm * 16 + g * 4 + r;
          const float mdv = drefsA[lrow];
          const float mr = mrwA[lrow];
          const float amx = fmaxf(2.5f * mxA[lrow], 0.f);
          float se = 0.f, sem = 0.f, smd = 0.f;
#pragma unroll
          for (int tn = 0; tn < 6; ++tn) {
            float post = acc[tm][tn][r];
            float gg = __expf(-fabsf(mdv - dvc[tn])) - BBC;
            float pre = post / (post > 0.f ? 1.f + gg : 1.f - gg);
            float pm = mr * mcr[tn];
            pre = (pm > 0.f) ? pre : NEGV;
            float e = __expf(pre - amx);
            se += e; sem += e * pm; smd += e * pm * dvc[tn];
          }
#pragma unroll
          for (int o = 1; o < 16; o <<= 1) {
            se += __shfl_xor(se, o, 16);
            sem += __shfl_xor(sem, o, 16);
            smd += __shfl_xor(smd, o, 16);
          }
          if (l15 == 0) { psum[lrow][w] = se; psem[lrow][w] = sem; asmd[lrow][w] = smd; }
        }
    }
    __syncthreads();
    if (t < 32) {
      float se = psum[t][0] + psum[t][1] + psum[t][2] + psum[t][3];
      float sem = psem[t][0] + psem[t][1] + psem[t][2] + psem[t][3];
      float smd = asmd[t][0] + asmd[t][1] + asmd[t][2] + asmd[t][3];
      md_rows[(size_t)bh * A + (r0 + t - V)] = smd / (sem + 1e-13f * se);
    }
    __syncthreads();
  }

  // ---- main softmax sums ----
#pragma unroll
  for (int tm = 0; tm < 2; ++tm)
#pragma unroll
    for (int r = 0; r < 4; ++r) {
      const int lrow = tm * 16 + g * 4 + r;
      const float mx = mxA[lrow];
      const float mr = mrwA[lrow];
      float se = 0.f, sem = 0.f;
#pragma unroll
      for (int tn = 0; tn < 6; ++tn) {
        float e = __expf(acc[tm][tn][r] - mx);
        acc[tm][tn][r] = e;
        se += e; sem += e * (mr * mcr[tn]);
      }
#pragma unroll
      for (int o = 1; o < 16; o <<= 1) {
        se += __shfl_xor(se, o, 16);
        sem += __shfl_xor(sem, o, 16);
      }
      if (l15 == 0) { psum[lrow][w] = se; psem[lrow][w] = sem; }
    }
  __syncthreads();
  if (t < 32) {
    float se = 0.f, sem = 0.f;
#pragma unroll
    for (int u = 0; u < 8; ++u) { se += psum[t][u]; sem += psem[t][u]; }
    rdA[t] = 1.f / (sem + 1e-13f * se);
  }
  __syncthreads();

  // ---- p writeout + swizzled bf16 P ----
#pragma unroll
  for (int tm = 0; tm < 2; ++tm)
#pragma unroll
    for (int r = 0; r < 4; ++r) {
      const int lrow = tm * 16 + g * 4 + r;
      const int row = r0 + lrow;
      const float rden = rdA[lrow];
      const float mr = mrwA[lrow];
      float* prow = &att_map[((size_t)bh * S + row) * S];
      const int swz = (lrow & 7) << 4;
#pragma unroll
      for (int tn = 0; tn < 6; ++tn) {
        const int col = w * 96 + tn * 16 + l15;
        float p = acc[tm][tn][r] * (mr * mcr[tn]) * rden;
        prow[col] = p;
        Ps[lrow][col ^ swz] = f2bf(p);
      }
    }
  __syncthreads();

  // ---- PV ----
  {
    const int ptm = w >> 2, ptn = w & 3;
    const int arow = ptm * 16 + l15;
    const int aswz = (arow & 7) << 4;
    f32x4 pacc = {};
    const unsigned short* vcol = &vhT[((size_t)bh * D + ptn * 16 + l15) * S];
#pragma unroll 8
    for (int kk = 0; kk < 24; ++kk) {
      short8 a = *(short8*)&Ps[arow][(kk * 32 + g * 8) ^ aswz];
      short8 bv = *(const short8*)&vcol[kk * 32 + g * 8];
      pacc = mfma16(a, bv, pacc);
    }
#pragma unroll
    for (int r = 0; r < 4; ++r) {
      const int row = r0 + ptm * 16 + g * 4 + r;
      ctx[((size_t)bh * S + row) * D + ptn * 16 + l15] = f2bf(pacc[r]);
    }
  }
}

// ---------------- md finalize ----------------
__global__ __launch_bounds__(256) void md_finalize(const float* __restrict__ md_rows,
                                                   const float* __restrict__ va_a_mask,
                                                   float* __restrict__ md_out) {
  __shared__ float red0[256];
  __shared__ float red1[256];
  const int b = blockIdx.x;
  const int t = threadIdx.x;
  float s1 = 0.f, s2 = 0.f;
  for (int u = t; u < H * A; u += 256) s1 += md_rows[(size_t)b * H * A + u];
  for (int u = t; u < A; u += 256) s2 += va_a_mask[(size_t)b * A + u];
  red0[t] = s1; red1[t] = s2;
  __syncthreads();
  for (int o = 128; o > 0; o >>= 1) {
    if (t < o) { red0[t] += red0[t + o]; red1[t] += red1[t + o]; }
    __syncthreads();
  }
  const float val = red0[0] / ((float)H * red1[0]);
  for (int u = t; u < A; u += 256) md_out[(size_t)b * A + u] = val;
}

extern "C" void kernel_launch(void* const* d_in, const int* in_sizes, int n_in,
                              void* d_out, int out_size, void* d_ws, size_t ws_size,
                              hipStream_t stream) {
  const float* q           = (const float*)d_in[0];
  const float* k           = (const float*)d_in[1];
  const float* v           = (const float*)d_in[2];
  const float* mask        = (const float*)d_in[3];
  const float* depth_value = (const float*)d_in[4];
  const float* va_a_mask   = (const float*)d_in[7];
  const float* mean_depth  = (const float*)d_in[8];
  const float* Wq = (const float*)d_in[9];
  const float* bq = (const float*)d_in[10];
  const float* Wk = (const float*)d_in[11];
  const float* bk = (const float*)d_in[12];
  const float* Wv = (const float*)d_in[13];
  const float* bv = (const float*)d_in[14];
  const float* Wo = (const float*)d_in[15];
  const float* bo = (const float*)d_in[16];

  unsigned short* wsu = (unsigned short*)d_ws;
  unsigned short* qh_hi = wsu;                 // aliased by ctx after score phase
  unsigned short* qh_lo = wsu + N_QH;
  unsigned short* kh_hi = wsu + 2 * N_QH;
  unsigned short* kh_lo = wsu + 3 * N_QH;
  unsigned short* vhT   = wsu + 4 * N_QH;
  unsigned short* ctx   = qh_hi;               // alias (per-row ownership matches)
  unsigned short* wt    = wsu + 5 * N_QH;      // 4 weights x (hi+lo) x 262144
  float* md_rows = (float*)(wsu + 5 * N_QH + 4 * 524288);

  float* out       = (float*)d_out;
  float* att_score = out + (size_t)B * S * HD;
  float* att_map   = att_score + (size_t)B * H * S * S;
  float* md_out    = att_map + (size_t)B * H * S * S;

  // x hi/lo split planes live in the (not-yet-written) att_score region: 37.7 MB of 151 MB
  unsigned short* xs = (unsigned short*)att_score;

  prep_all<<<544, 256, 0, stream>>>(Wq, Wk, Wv, Wo, q, k, v, wt, xs);
  qkv_mfma<<<dim3(96, 8, 3), 256, 0, stream>>>(xs, wt, bq, bk, bv,
                                               qh_hi, qh_lo, kh_hi, kh_lo, vhT);
  fused_attn<<<1536, 512, 0, stream>>>(qh_hi, qh_lo, kh_hi, kh_lo, vhT, mask,
                                       depth_value, mean_depth, att_score,
                                       att_map, ctx, md_rows);
  gemm_out<<<dim3(96, 8), 256, 0, stream>>>(ctx, wt + 3 * 524288, wt + 3 * 524288 + 262144,
                                            bo, out);
  md_finalize<<<B, 256, 0, stream>>>(md_rows, va_a_mask, md_out);
}

// Round 7
// 184.136 us; speedup vs baseline: 4.5910x; 1.2384x over previous
//
#include <hip/hip_runtime.h>
#include <hip/hip_bf16.h>
#include <cstdint>
#include <cstddef>

namespace {
constexpr int B  = 8;
constexpr int S  = 768;
constexpr int V  = 384;
constexpr int A  = 384;
constexpr int H  = 8;
constexpr int D  = 64;
constexpr int HD = 512;
constexpr float SCALE = 0.125f;       // d^-0.5, d=64
constexpr float BBC   = 0.6f;
constexpr float NEGV  = -1000000000.0f;
constexpr size_t N_QH = (size_t)B * H * S * D;   // 3145728 (= 6144*512)
}

using short8 = __attribute__((ext_vector_type(8))) short;
using f32x4  = __attribute__((ext_vector_type(4))) float;

static __device__ __forceinline__ unsigned short f2bf(float f) {
  union { float f; unsigned int u; } v; v.f = f;
  unsigned int r = v.u + 0x7FFFu + ((v.u >> 16) & 1u);
  return (unsigned short)(r >> 16);
}
static __device__ __forceinline__ f32x4 mfma16(short8 a, short8 b, f32x4 c) {
  return __builtin_amdgcn_mfma_f32_16x16x32_bf16(a, b, c, 0, 0, 0);
}

// ---------------- prep_all: W -> hi/lo [n][k] bf16; q/k/v -> single bf16 ----------
// grid 544: id<256 -> weight tiles (z=id>>6); id>=256 -> x convert (3 x 96)
__global__ __launch_bounds__(256) void prep_all(
    const float* __restrict__ Wq, const float* __restrict__ Wk,
    const float* __restrict__ Wv, const float* __restrict__ Wo,
    const float* __restrict__ q, const float* __restrict__ k,
    const float* __restrict__ v,
    unsigned short* __restrict__ wt, unsigned short* __restrict__ xs)
{
  const int id = blockIdx.x;
  const int t = threadIdx.x;
  if (id < 256) {
    __shared__ float tile[64][68];
    const int z = id >> 6, tl = id & 63;
    const int k0 = (tl >> 3) * 64, n0 = (tl & 7) * 64;
    const float* W = (z == 0) ? Wq : (z == 1) ? Wk : (z == 2) ? Wv : Wo;
    unsigned short* WTh = wt + (size_t)z * 524288;
    unsigned short* WTl = WTh + 262144;
#pragma unroll
    for (int u = 0; u < 4; ++u) {
      int idx = u * 256 + t;
      int r = idx >> 4, c4 = (idx & 15) * 4;
      *(float4*)&tile[r][c4] = *(const float4*)&W[(size_t)(k0 + r) * 512 + n0 + c4];
    }
    __syncthreads();
#pragma unroll
    for (int u = 0; u < 4; ++u) {
      int idx = u * 256 + t;
      int n = idx >> 4, kq = (idx & 15) * 4;
      unsigned int uh[4], ul[4];
#pragma unroll
      for (int j = 0; j < 4; ++j) {
        float x = tile[kq + j][n];
        unsigned int ux = __float_as_uint(x);
        uh[j] = ux >> 16;
        float r = x - __uint_as_float(ux & 0xFFFF0000u);
        ul[j] = __float_as_uint(r) >> 16;
      }
      *(uint2*)&WTh[(size_t)(n0 + n) * 512 + k0 + kq] =
          make_uint2(uh[0] | (uh[1] << 16), uh[2] | (uh[3] << 16));
      *(uint2*)&WTl[(size_t)(n0 + n) * 512 + k0 + kq] =
          make_uint2(ul[0] | (ul[1] << 16), ul[2] | (ul[3] << 16));
    }
  } else {
    const int m = id - 256;
    const int z = m / 96, rb = m % 96;
    const float* X = (z == 0) ? q : (z == 1) ? k : v;
    unsigned short* xh = xs + (size_t)z * N_QH;
#pragma unroll 4
    for (int u = 0; u < 32; ++u) {
      int idx = u * 256 + t;
      int row = idx >> 7, c = (idx & 127) * 4;
      size_t base = (size_t)(rb * 64 + row) * 512 + c;
      float4 xv = *(const float4*)&X[base];
      unsigned int h0 = f2bf(xv.x), h1 = f2bf(xv.y), h2 = f2bf(xv.z), h3 = f2bf(xv.w);
      *(uint2*)&xh[base] = make_uint2(h0 | (h1 << 16), h2 | (h3 << 16));
    }
  }
}

// ---------------- qkv projections: X bf16 @ W(hi/lo) 2-pass MFMA ----------------
// 1D grid 2304, chunked-XCD swizzle; outputs single bf16 (q/k head-layout, v transposed)
__global__ __launch_bounds__(256) void qkv_mfma(
    const unsigned short* __restrict__ xs, const unsigned short* __restrict__ wt,
    const float* __restrict__ bq, const float* __restrict__ bk,
    const float* __restrict__ bv,
    unsigned short* __restrict__ qh, unsigned short* __restrict__ kh,
    unsigned short* __restrict__ vhT)
{
  __shared__ unsigned short Ah[64][40];
  __shared__ unsigned short Bh[64][40];
  __shared__ unsigned short Bl[64][40];
  const int lin = ((blockIdx.x & 7) * 288) + (blockIdx.x >> 3);
  const int n0 = (lin & 7) * 64;
  const int gidx = lin >> 3;          // 0..287
  const int mt = gidx % 96, z = gidx / 96;
  const int m0 = mt * 64;
  const unsigned short* Xh = xs + (size_t)z * N_QH;
  const unsigned short* WTh = wt + (size_t)z * 524288;
  const unsigned short* WTl = WTh + 262144;
  const float* bias = (z == 0) ? bq : (z == 1) ? bk : bv;
  const int t = threadIdx.x, w = t >> 6, lane = t & 63;
  const int l15 = lane & 15, g = lane >> 4;
  const int bb = m0 / S;
  f32x4 acc[4] = {};

  const int srow = t >> 2, skq = (t & 3) * 8;
  for (int k0 = 0; k0 < 512; k0 += 32) {
    __syncthreads();
    *(short8*)&Ah[srow][skq] = *(const short8*)&Xh[(size_t)(m0 + srow) * 512 + k0 + skq];
    *(short8*)&Bh[srow][skq] = *(const short8*)&WTh[(size_t)(n0 + srow) * 512 + k0 + skq];
    *(short8*)&Bl[srow][skq] = *(const short8*)&WTl[(size_t)(n0 + srow) * 512 + k0 + skq];
    __syncthreads();
    if (z != 2) {
      short8 ah = *(short8*)&Ah[w * 16 + l15][g * 8];
#pragma unroll
      for (int tn = 0; tn < 4; ++tn) {
        short8 bh_ = *(short8*)&Bh[tn * 16 + l15][g * 8];
        short8 bl_ = *(short8*)&Bl[tn * 16 + l15][g * 8];
        acc[tn] = mfma16(ah, bl_, acc[tn]);
        acc[tn] = mfma16(ah, bh_, acc[tn]);
      }
    } else {  // swapped operands: D[n][m] -> coalesced vhT stores
      short8 wh = *(short8*)&Bh[w * 16 + l15][g * 8];
      short8 wl = *(short8*)&Bl[w * 16 + l15][g * 8];
#pragma unroll
      for (int tm = 0; tm < 4; ++tm) {
        short8 xf = *(short8*)&Ah[tm * 16 + l15][g * 8];
        acc[tm] = mfma16(wl, xf, acc[tm]);
        acc[tm] = mfma16(wh, xf, acc[tm]);
      }
    }
  }

  if (z != 2) {
    unsigned short* Y = (z == 0) ? qh : kh;
#pragma unroll
    for (int tn = 0; tn < 4; ++tn) {
      const int c = n0 + tn * 16 + l15;
      const float bi = bias[c];
      const int h = c >> 6, d = c & 63;
#pragma unroll
      for (int r = 0; r < 4; ++r) {
        const int mm = m0 + w * 16 + g * 4 + r;
        const int s = mm - bb * S;
        Y[((size_t)(bb * H + h) * S + s) * D + d] = f2bf(acc[tn][r] + bi);
      }
    }
  } else {
#pragma unroll
    for (int tm = 0; tm < 4; ++tm) {
      const int mcol = m0 + tm * 16 + l15;
      const int s = mcol - bb * S;
#pragma unroll
      for (int r = 0; r < 4; ++r) {
        const int n = n0 + w * 16 + g * 4 + r;
        const int h = n >> 6, d = n & 63;
        vhT[((size_t)(bb * H + h) * D + d) * S + s] = f2bf(acc[tm][r] + bias[n]);
      }
    }
  }
}

// ---------------- fused attention: 16 rows x 768 cols per 4-wave block ----------
// 1D grid 3072, XCD-swizzled: bh = (id&7) + 8*((id>>3)/48), rt = (id>>3)%48
__global__ __launch_bounds__(256, 4) void fused_attn(
    const unsigned short* __restrict__ qh, const unsigned short* __restrict__ kh,
    const unsigned short* __restrict__ vhT,
    const float* __restrict__ mask, const float* __restrict__ depth_value,
    const float* __restrict__ mean_depth,
    float* __restrict__ att_score, float* __restrict__ att_map,
    unsigned short* __restrict__ ctx, float* __restrict__ md_rows)
{
  __shared__ unsigned short Ps[16][768];   // XOR-swizzled bf16 P tile (24 KB)
  __shared__ float mcol[768];
  __shared__ float dvcol[384];
  __shared__ float pmax[16][4];
  __shared__ float psum[16][4];
  __shared__ float psem[16][4];
  __shared__ float asmd[16][2];
  __shared__ float mxA[16], rdA[16], drefsA[16], mrwA[16];

  const int id = blockIdx.x;
  const int rest = id >> 3;
  const int rt = rest % 48;
  const int bh = (id & 7) + 8 * (rest / 48);
  const int b = bh >> 3, b0 = b >> 2;
  const int r0 = rt * 16;
  const int t = threadIdx.x;
  const int w = t >> 6;
  const int lane = t & 63;
  const int l15 = lane & 15, g = lane >> 4;
  const bool avblk = (r0 >= V);

  for (int j = t; j < 768; j += 256) mcol[j] = mask[(size_t)b * S + j];
  for (int j = t; j < 384; j += 256) dvcol[j] = depth_value[(size_t)b0 * V + j];
  if (t < 16) {
    const int row = r0 + t;
    drefsA[t] = (row < V) ? depth_value[(size_t)b0 * V + row]
                          : mean_depth[(size_t)b * A + (row - V)];
    mrwA[t] = mask[(size_t)b * S + row];
  }

  // Q fragments (single bf16), rows r0..r0+15
  short8 qf[2];
#pragma unroll
  for (int ks = 0; ks < 2; ++ks)
    qf[ks] = *(const short8*)&qh[((size_t)bh * S + r0 + l15) * D + ks * 32 + g * 8];

  // ---- scores: 1-pass bf16 MFMA; wave w owns cols [w*192, w*192+192) ----
  f32x4 acc[12] = {};
#pragma unroll
  for (int tn = 0; tn < 12; ++tn) {
    const int col = w * 192 + tn * 16 + l15;
#pragma unroll
    for (int ks = 0; ks < 2; ++ks) {
      short8 kf = *(const short8*)&kh[((size_t)bh * S + col) * D + ks * 32 + g * 8];
      acc[tn] = mfma16(qf[ks], kf, acc[tn]);
    }
  }
  __syncthreads();   // LDS stage ready

  const bool biasw = (w < 2);   // cols < V
  float mcr[12], dvc[12];
#pragma unroll
  for (int tn = 0; tn < 12; ++tn) {
    const int col = w * 192 + tn * 16 + l15;
    mcr[tn] = mcol[col];
    dvc[tn] = biasw ? dvcol[col] : 0.f;
  }

  // ---- epilogue: scale + depth bias + mask; write att_score; keep x in regs ----
#pragma unroll
  for (int r = 0; r < 4; ++r) {
    const int lrow = g * 4 + r;
    const int row = r0 + lrow;
    const float mr = mrwA[lrow];
    const float dref = drefsA[lrow];
    float* srow = &att_score[((size_t)bh * S + row) * S];
#pragma unroll
    for (int tn = 0; tn < 12; ++tn) {
      const int col = w * 192 + tn * 16 + l15;
      float x = acc[tn][r] * SCALE;
      if (biasw) {
        float gg = __expf(-fabsf(dref - dvc[tn])) - BBC;
        float bb2 = fabsf(x) * gg;
        if (row == col) bb2 = 0.f;
        x += bb2;
      }
      x = (mr * mcr[tn] > 0.f) ? x : NEGV;
      srow[col] = x;
      acc[tn][r] = x;
    }
  }

  // ---- main row max ----
#pragma unroll
  for (int r = 0; r < 4; ++r) {
    float v = NEGV;
#pragma unroll
    for (int tn = 0; tn < 12; ++tn) v = fmaxf(v, acc[tn][r]);
#pragma unroll
    for (int o = 1; o < 16; o <<= 1) v = fmaxf(v, __shfl_xor(v, o, 16));
    if (l15 == 0) pmax[g * 4 + r][w] = v;
  }
  __syncthreads();
  if (t < 16)
    mxA[t] = fmaxf(fmaxf(pmax[t][0], pmax[t][1]), fmaxf(pmax[t][2], pmax[t][3]));
  __syncthreads();

  // ---- AV (pre-bias) softmax + md: single pass, bounded-max trick ----
  if (avblk) {
    if (biasw) {
#pragma unroll
      for (int r = 0; r < 4; ++r) {
        const int lrow = g * 4 + r;
        const float mdv = drefsA[lrow];
        const float mr = mrwA[lrow];
        const float amx = fmaxf(2.5f * mxA[lrow], 0.f);
        float se = 0.f, sem = 0.f, smd = 0.f;
#pragma unroll
        for (int tn = 0; tn < 12; ++tn) {
          float post = acc[tn][r];
          float gg = __expf(-fabsf(mdv - dvc[tn])) - BBC;
          float pre = post / (post > 0.f ? 1.f + gg : 1.f - gg);
          float pm = mr * mcr[tn];
          pre = (pm > 0.f) ? pre : NEGV;
          float e = __expf(pre - amx);
          se += e; sem += e * pm; smd += e * pm * dvc[tn];
        }
#pragma unroll
        for (int o = 1; o < 16; o <<= 1) {
          se += __shfl_xor(se, o, 16);
          sem += __shfl_xor(sem, o, 16);
          smd += __shfl_xor(smd, o, 16);
        }
        if (l15 == 0) { psum[lrow][w] = se; psem[lrow][w] = sem; asmd[lrow][w] = smd; }
      }
    }
    __syncthreads();
    if (t < 16) {
      float se = psum[t][0] + psum[t][1];
      float sem = psem[t][0] + psem[t][1];
      float smd = asmd[t][0] + asmd[t][1];
      md_rows[(size_t)bh * A + (r0 + t - V)] = smd / (sem + 1e-13f * se);
    }
    __syncthreads();
  }

  // ---- main softmax sums ----
#pragma unroll
  for (int r = 0; r < 4; ++r) {
    const int lrow = g * 4 + r;
    const float mx = mxA[lrow];
    const float mr = mrwA[lrow];
    float se = 0.f, sem = 0.f;
#pragma unroll
    for (int tn = 0; tn < 12; ++tn) {
      float e = __expf(acc[tn][r] - mx);
      acc[tn][r] = e;
      se += e; sem += e * (mr * mcr[tn]);
    }
#pragma unroll
    for (int o = 1; o < 16; o <<= 1) {
      se += __shfl_xor(se, o, 16);
      sem += __shfl_xor(sem, o, 16);
    }
    if (l15 == 0) { psum[lrow][w] = se; psem[lrow][w] = sem; }
  }
  __syncthreads();
  if (t < 16) {
    float se = psum[t][0] + psum[t][1] + psum[t][2] + psum[t][3];
    float sem = psem[t][0] + psem[t][1] + psem[t][2] + psem[t][3];
    rdA[t] = 1.f / (sem + 1e-13f * se);
  }
  __syncthreads();

  // ---- p writeout + swizzled bf16 P ----
#pragma unroll
  for (int r = 0; r < 4; ++r) {
    const int lrow = g * 4 + r;
    const int row = r0 + lrow;
    const float rden = rdA[lrow];
    const float mr = mrwA[lrow];
    float* prow = &att_map[((size_t)bh * S + row) * S];
    const int swz = (lrow & 7) << 4;
#pragma unroll
    for (int tn = 0; tn < 12; ++tn) {
      const int col = w * 192 + tn * 16 + l15;
      float p = acc[tn][r] * (mr * mcr[tn]) * rden;
      prow[col] = p;
      Ps[lrow][col ^ swz] = f2bf(p);
    }
  }
  __syncthreads();

  // ---- PV: ctx(16x64) = P(16x768) @ V(768x64); wave w owns d block [w*16, w*16+16) ----
  {
    const int aswz = (l15 & 7) << 4;
    f32x4 pacc = {};
    const unsigned short* vcol = &vhT[((size_t)bh * D + w * 16 + l15) * S];
#pragma unroll 8
    for (int kk = 0; kk < 24; ++kk) {
      short8 a = *(short8*)&Ps[l15][(kk * 32 + g * 8) ^ aswz];
      short8 bv = *(const short8*)&vcol[kk * 32 + g * 8];
      pacc = mfma16(a, bv, pacc);
    }
#pragma unroll
    for (int r = 0; r < 4; ++r) {
      const int row = r0 + g * 4 + r;
      ctx[((size_t)bh * S + row) * D + w * 16 + l15] = f2bf(pacc[r]);
    }
  }
}

// ---------------- out projection (+ fused md finalize) ----------------
// 1D grid 776: id<768 -> GEMM tile (chunked-XCD swizzle); id>=768 -> md for b=id-768
__global__ __launch_bounds__(256) void gemm_out(
    const unsigned short* __restrict__ Xb, const unsigned short* __restrict__ WTh,
    const unsigned short* __restrict__ WTl, const float* __restrict__ bias,
    float* __restrict__ Yf,
    const float* __restrict__ md_rows, const float* __restrict__ va_a_mask,
    float* __restrict__ md_out)
{
  const int t = threadIdx.x;
  if (blockIdx.x >= 768) {
    __shared__ float red0[256];
    __shared__ float red1[256];
    const int b = blockIdx.x - 768;
    float s1 = 0.f, s2 = 0.f;
    for (int u = t; u < H * A; u += 256) s1 += md_rows[(size_t)b * H * A + u];
    for (int u = t; u < A; u += 256) s2 += va_a_mask[(size_t)b * A + u];
    red0[t] = s1; red1[t] = s2;
    __syncthreads();
    for (int o = 128; o > 0; o >>= 1) {
      if (t < o) { red0[t] += red0[t + o]; red1[t] += red1[t + o]; }
      __syncthreads();
    }
    const float val = red0[0] / ((float)H * red1[0]);
    for (int u = t; u < A; u += 256) md_out[(size_t)b * A + u] = val;
    return;
  }
  __shared__ unsigned short Ah[64][40];
  __shared__ unsigned short Bh[64][40];
  __shared__ unsigned short Bl[64][40];
  const int lin = ((blockIdx.x & 7) * 96) + (blockIdx.x >> 3);
  const int n0 = (lin & 7) * 64;
  const int m0 = (lin >> 3) * 64;
  const int w = t >> 6, lane = t & 63;
  const int l15 = lane & 15, g = lane >> 4;
  const int bb = m0 / S;
  f32x4 acc[4] = {};
  const int srow = t >> 2, skq = (t & 3) * 8;
  for (int k0 = 0; k0 < 512; k0 += 32) {
    __syncthreads();
    {
      const int s = m0 + srow - bb * S;
      const int h = k0 >> 6, d = (k0 & 63) + skq;
      *(short8*)&Ah[srow][skq] = *(const short8*)&Xb[((size_t)(bb * H + h) * S + s) * D + d];
    }
    *(short8*)&Bh[srow][skq] = *(const short8*)&WTh[(size_t)(n0 + srow) * 512 + k0 + skq];
    *(short8*)&Bl[srow][skq] = *(const short8*)&WTl[(size_t)(n0 + srow) * 512 + k0 + skq];
    __syncthreads();
    short8 ah = *(short8*)&Ah[w * 16 + l15][g * 8];
#pragma unroll
    for (int tn = 0; tn < 4; ++tn) {
      short8 bh_ = *(short8*)&Bh[tn * 16 + l15][g * 8];
      short8 bl_ = *(short8*)&Bl[tn * 16 + l15][g * 8];
      acc[tn] = mfma16(ah, bl_, acc[tn]);
      acc[tn] = mfma16(ah, bh_, acc[tn]);
    }
  }
#pragma unroll
  for (int tn = 0; tn < 4; ++tn) {
    const int c = n0 + tn * 16 + l15;
    const float bi = bias[c];
#pragma unroll
    for (int r = 0; r < 4; ++r) {
      const int m = m0 + w * 16 + g * 4 + r;
      Yf[(size_t)m * 512 + c] = acc[tn][r] + bi;
    }
  }
}

extern "C" void kernel_launch(void* const* d_in, const int* in_sizes, int n_in,
                              void* d_out, int out_size, void* d_ws, size_t ws_size,
                              hipStream_t stream) {
  const float* q           = (const float*)d_in[0];
  const float* k           = (const float*)d_in[1];
  const float* v           = (const float*)d_in[2];
  const float* mask        = (const float*)d_in[3];
  const float* depth_value = (const float*)d_in[4];
  const float* va_a_mask   = (const float*)d_in[7];
  const float* mean_depth  = (const float*)d_in[8];
  const float* Wq = (const float*)d_in[9];
  const float* bq = (const float*)d_in[10];
  const float* Wk = (const float*)d_in[11];
  const float* bk = (const float*)d_in[12];
  const float* Wv = (const float*)d_in[13];
  const float* bv = (const float*)d_in[14];
  const float* Wo = (const float*)d_in[15];
  const float* bo = (const float*)d_in[16];

  unsigned short* wsu = (unsigned short*)d_ws;
  unsigned short* qh  = wsu;                 // aliased by ctx after q-frag reads
  unsigned short* kh  = wsu + N_QH;
  unsigned short* vhT = wsu + 2 * N_QH;
  unsigned short* ctx = qh;                  // alias (per-row ownership matches)
  unsigned short* wt  = wsu + 3 * N_QH;      // 4 weights x (hi+lo) x 262144
  float* md_rows = (float*)(wsu + 3 * N_QH + 4 * 524288);

  float* out       = (float*)d_out;
  float* att_score = out + (size_t)B * S * HD;
  float* att_map   = att_score + (size_t)B * H * S * S;
  float* md_out    = att_map + (size_t)B * H * S * S;

  // x bf16 planes live in the (not-yet-written) att_score region: 18.9 MB of 151 MB
  unsigned short* xs = (unsigned short*)att_score;

  prep_all<<<544, 256, 0, stream>>>(Wq, Wk, Wv, Wo, q, k, v, wt, xs);
  qkv_mfma<<<2304, 256, 0, stream>>>(xs, wt, bq, bk, bv, qh, kh, vhT);
  fused_attn<<<3072, 256, 0, stream>>>(qh, kh, vhT, mask, depth_value, mean_depth,
                                       att_score, att_map, ctx, md_rows);
  gemm_out<<<776, 256, 0, stream>>>(ctx, wt + 3 * 524288, wt + 3 * 524288 + 262144,
                                    bo, out, md_rows, va_a_mask, md_out);
}

// Round 8
// 172.188 us; speedup vs baseline: 4.9095x; 1.0694x over previous
//
#include <hip/hip_runtime.h>
#include <hip/hip_bf16.h>
#include <cstdint>
#include <cstddef>

namespace {
constexpr int B  = 8;
constexpr int S  = 768;
constexpr int V  = 384;
constexpr int A  = 384;
constexpr int H  = 8;
constexpr int D  = 64;
constexpr int HD = 512;
constexpr float SCALE = 0.125f;       // d^-0.5, d=64
constexpr float BBC   = 0.6f;
constexpr float NEGV  = -1000000000.0f;
constexpr size_t N_QH = (size_t)B * H * S * D;   // 3145728 (= 6144*512)
}

using short8 = __attribute__((ext_vector_type(8))) short;
using f32x4  = __attribute__((ext_vector_type(4))) float;

static __device__ __forceinline__ unsigned short f2bf(float f) {
  union { float f; unsigned int u; } v; v.f = f;
  unsigned int r = v.u + 0x7FFFu + ((v.u >> 16) & 1u);
  return (unsigned short)(r >> 16);
}
static __device__ __forceinline__ f32x4 mfma16(short8 a, short8 b, f32x4 c) {
  return __builtin_amdgcn_mfma_f32_16x16x32_bf16(a, b, c, 0, 0, 0);
}
static __device__ __forceinline__ short8 pack_bf8(float4 a, float4 b) {
  union { short8 s; uint4 u; } r;
  r.u.x = (unsigned)f2bf(a.x) | ((unsigned)f2bf(a.y) << 16);
  r.u.y = (unsigned)f2bf(a.z) | ((unsigned)f2bf(a.w) << 16);
  r.u.z = (unsigned)f2bf(b.x) | ((unsigned)f2bf(b.y) << 16);
  r.u.w = (unsigned)f2bf(b.z) | ((unsigned)f2bf(b.w) << 16);
  return r.s;
}

// ---------------- prep_w: W[k][n] f32 -> WT bf16 [n][k] (RTN), 4 weights ----------
__global__ __launch_bounds__(256) void prep_w(
    const float* __restrict__ Wq, const float* __restrict__ Wk,
    const float* __restrict__ Wv, const float* __restrict__ Wo,
    unsigned short* __restrict__ wt)
{
  __shared__ float tile[64][68];
  const int id = blockIdx.x;           // 0..255
  const int z = id >> 6, tl = id & 63;
  const int k0 = (tl >> 3) * 64, n0 = (tl & 7) * 64;
  const float* W = (z == 0) ? Wq : (z == 1) ? Wk : (z == 2) ? Wv : Wo;
  unsigned short* WT = wt + (size_t)z * 262144;
  const int t = threadIdx.x;
#pragma unroll
  for (int u = 0; u < 4; ++u) {
    int idx = u * 256 + t;
    int r = idx >> 4, c4 = (idx & 15) * 4;
    *(float4*)&tile[r][c4] = *(const float4*)&W[(size_t)(k0 + r) * 512 + n0 + c4];
  }
  __syncthreads();
#pragma unroll
  for (int u = 0; u < 4; ++u) {
    int idx = u * 256 + t;
    int n = idx >> 4, kq = (idx & 15) * 4;
    unsigned int h0 = f2bf(tile[kq + 0][n]), h1 = f2bf(tile[kq + 1][n]);
    unsigned int h2 = f2bf(tile[kq + 2][n]), h3 = f2bf(tile[kq + 3][n]);
    *(uint2*)&WT[(size_t)(n0 + n) * 512 + k0 + kq] =
        make_uint2(h0 | (h1 << 16), h2 | (h3 << 16));
  }
}

// ---------------- qkv projections: f32 X direct, bf16 W in LDS, 1-pass MFMA ------
// 1D grid 2304, chunked-XCD swizzle; outputs bf16 (q/k head-layout, v transposed)
__global__ __launch_bounds__(256) void qkv_mfma(
    const float* __restrict__ q, const float* __restrict__ k,
    const float* __restrict__ v, const unsigned short* __restrict__ wt,
    const float* __restrict__ bq, const float* __restrict__ bk,
    const float* __restrict__ bv,
    unsigned short* __restrict__ qh, unsigned short* __restrict__ kh,
    unsigned short* __restrict__ vhT)
{
  __shared__ unsigned short Bh[64][40];
  __shared__ unsigned short Ax[64][40];   // used only for z==2
  const int lin = ((blockIdx.x & 7) * 288) + (blockIdx.x >> 3);
  const int n0 = (lin & 7) * 64;
  const int gidx = lin >> 3;          // 0..287
  const int mt = gidx % 96, z = gidx / 96;
  const int m0 = mt * 64;
  const float* X = (z == 0) ? q : (z == 1) ? k : v;
  const unsigned short* WT = wt + (size_t)z * 262144;
  const float* bias = (z == 0) ? bq : (z == 1) ? bk : bv;
  const int t = threadIdx.x, w = t >> 6, lane = t & 63;
  const int l15 = lane & 15, g = lane >> 4;
  const int bb = m0 / S;
  f32x4 acc[4] = {};

  const int srow = t >> 2, skq = (t & 3) * 8;
  for (int k0 = 0; k0 < 512; k0 += 32) {
    __syncthreads();
    *(short8*)&Bh[srow][skq] = *(const short8*)&WT[(size_t)(n0 + srow) * 512 + k0 + skq];
    if (z == 2) {
      float4 x0 = *(const float4*)&X[(size_t)(m0 + srow) * 512 + k0 + skq];
      float4 x1 = *(const float4*)&X[(size_t)(m0 + srow) * 512 + k0 + skq + 4];
      *(short8*)&Ax[srow][skq] = pack_bf8(x0, x1);
    }
    __syncthreads();
    if (z != 2) {
      const size_t abase = (size_t)(m0 + w * 16 + l15) * 512 + k0 + g * 8;
      float4 a0 = *(const float4*)&X[abase];
      float4 a1 = *(const float4*)&X[abase + 4];
      short8 ah = pack_bf8(a0, a1);
#pragma unroll
      for (int tn = 0; tn < 4; ++tn) {
        short8 bh_ = *(short8*)&Bh[tn * 16 + l15][g * 8];
        acc[tn] = mfma16(ah, bh_, acc[tn]);
      }
    } else {  // swapped operands: D[n][m] -> coalesced vhT stores
      short8 wh = *(short8*)&Bh[w * 16 + l15][g * 8];
#pragma unroll
      for (int tm = 0; tm < 4; ++tm) {
        short8 xf = *(short8*)&Ax[tm * 16 + l15][g * 8];
        acc[tm] = mfma16(wh, xf, acc[tm]);
      }
    }
  }

  if (z != 2) {
    unsigned short* Y = (z == 0) ? qh : kh;
#pragma unroll
    for (int tn = 0; tn < 4; ++tn) {
      const int c = n0 + tn * 16 + l15;
      const float bi = bias[c];
      const int h = c >> 6, d = c & 63;
#pragma unroll
      for (int r = 0; r < 4; ++r) {
        const int mm = m0 + w * 16 + g * 4 + r;
        const int s = mm - bb * S;
        Y[((size_t)(bb * H + h) * S + s) * D + d] = f2bf(acc[tn][r] + bi);
      }
    }
  } else {
#pragma unroll
    for (int tm = 0; tm < 4; ++tm) {
      const int mcol = m0 + tm * 16 + l15;
      const int s = mcol - bb * S;
#pragma unroll
      for (int r = 0; r < 4; ++r) {
        const int n = n0 + w * 16 + g * 4 + r;
        const int h = n >> 6, d = n & 63;
        vhT[((size_t)(bb * H + h) * D + d) * S + s] = f2bf(acc[tm][r] + bias[n]);
      }
    }
  }
}

// ---------------- fused attention: 16 rows x 768 cols per 4-wave block ----------
// 1D grid 3072, XCD-swizzled: bh = (id&7) + 8*((id>>3)/48), rt = (id>>3)%48
__global__ __launch_bounds__(256, 4) void fused_attn(
    const unsigned short* __restrict__ qh, const unsigned short* __restrict__ kh,
    const unsigned short* __restrict__ vhT,
    const float* __restrict__ mask, const float* __restrict__ depth_value,
    const float* __restrict__ mean_depth,
    float* __restrict__ att_score, float* __restrict__ att_map,
    unsigned short* __restrict__ ctx, float* __restrict__ md_rows)
{
  __shared__ unsigned short Ps[16][768];   // XOR-swizzled bf16 P tile (24 KB)
  __shared__ float mcol[768];
  __shared__ float dvcol[384];
  __shared__ float pmax[16][4];
  __shared__ float psum[16][4];
  __shared__ float psem[16][4];
  __shared__ float asmd[16][2];
  __shared__ float mxA[16], rdA[16], drefsA[16], mrwA[16];

  const int id = blockIdx.x;
  const int rest = id >> 3;
  const int rt = rest % 48;
  const int bh = (id & 7) + 8 * (rest / 48);
  const int b = bh >> 3, b0 = b >> 2;
  const int r0 = rt * 16;
  const int t = threadIdx.x;
  const int w = t >> 6;
  const int lane = t & 63;
  const int l15 = lane & 15, g = lane >> 4;
  const bool avblk = (r0 >= V);

  for (int j = t; j < 768; j += 256) mcol[j] = mask[(size_t)b * S + j];
  for (int j = t; j < 384; j += 256) dvcol[j] = depth_value[(size_t)b0 * V + j];
  if (t < 16) {
    const int row = r0 + t;
    drefsA[t] = (row < V) ? depth_value[(size_t)b0 * V + row]
                          : mean_depth[(size_t)b * A + (row - V)];
    mrwA[t] = mask[(size_t)b * S + row];
  }

  // Q fragments (single bf16), rows r0..r0+15
  short8 qf[2];
#pragma unroll
  for (int ks = 0; ks < 2; ++ks)
    qf[ks] = *(const short8*)&qh[((size_t)bh * S + r0 + l15) * D + ks * 32 + g * 8];

  // ---- scores: 1-pass bf16 MFMA; wave w owns cols [w*192, w*192+192) ----
  f32x4 acc[12] = {};
#pragma unroll
  for (int tn = 0; tn < 12; ++tn) {
    const int col = w * 192 + tn * 16 + l15;
#pragma unroll
    for (int ks = 0; ks < 2; ++ks) {
      short8 kf = *(const short8*)&kh[((size_t)bh * S + col) * D + ks * 32 + g * 8];
      acc[tn] = mfma16(qf[ks], kf, acc[tn]);
    }
  }
  __syncthreads();   // LDS stage ready

  const bool biasw = (w < 2);   // cols < V
  float mcr[12], dvc[12];
#pragma unroll
  for (int tn = 0; tn < 12; ++tn) {
    const int col = w * 192 + tn * 16 + l15;
    mcr[tn] = mcol[col];
    dvc[tn] = biasw ? dvcol[col] : 0.f;
  }

  // ---- epilogue: scale + depth bias + mask; write att_score; keep x in regs ----
#pragma unroll
  for (int r = 0; r < 4; ++r) {
    const int lrow = g * 4 + r;
    const int row = r0 + lrow;
    const float mr = mrwA[lrow];
    const float dref = drefsA[lrow];
    float* srow = &att_score[((size_t)bh * S + row) * S];
#pragma unroll
    for (int tn = 0; tn < 12; ++tn) {
      const int col = w * 192 + tn * 16 + l15;
      float x = acc[tn][r] * SCALE;
      if (biasw) {
        float gg = __expf(-fabsf(dref - dvc[tn])) - BBC;
        float bb2 = fabsf(x) * gg;
        if (row == col) bb2 = 0.f;
        x += bb2;
      }
      x = (mr * mcr[tn] > 0.f) ? x : NEGV;
      __builtin_nontemporal_store(x, &srow[col]);
      acc[tn][r] = x;
    }
  }

  // ---- main row max ----
#pragma unroll
  for (int r = 0; r < 4; ++r) {
    float v = NEGV;
#pragma unroll
    for (int tn = 0; tn < 12; ++tn) v = fmaxf(v, acc[tn][r]);
#pragma unroll
    for (int o = 1; o < 16; o <<= 1) v = fmaxf(v, __shfl_xor(v, o, 16));
    if (l15 == 0) pmax[g * 4 + r][w] = v;
  }
  __syncthreads();
  if (t < 16)
    mxA[t] = fmaxf(fmaxf(pmax[t][0], pmax[t][1]), fmaxf(pmax[t][2], pmax[t][3]));
  __syncthreads();

  // ---- AV (pre-bias) softmax + md: single pass, bounded-max trick ----
  if (avblk) {
    if (biasw) {
#pragma unroll
      for (int r = 0; r < 4; ++r) {
        const int lrow = g * 4 + r;
        const float mdv = drefsA[lrow];
        const float mr = mrwA[lrow];
        const float amx = fmaxf(2.5f * mxA[lrow], 0.f);
        float se = 0.f, sem = 0.f, smd = 0.f;
#pragma unroll
        for (int tn = 0; tn < 12; ++tn) {
          float post = acc[tn][r];
          float gg = __expf(-fabsf(mdv - dvc[tn])) - BBC;
          float pre = post / (post > 0.f ? 1.f + gg : 1.f - gg);
          float pm = mr * mcr[tn];
          pre = (pm > 0.f) ? pre : NEGV;
          float e = __expf(pre - amx);
          se += e; sem += e * pm; smd += e * pm * dvc[tn];
        }
#pragma unroll
        for (int o = 1; o < 16; o <<= 1) {
          se += __shfl_xor(se, o, 16);
          sem += __shfl_xor(sem, o, 16);
          smd += __shfl_xor(smd, o, 16);
        }
        if (l15 == 0) { psum[lrow][w] = se; psem[lrow][w] = sem; asmd[lrow][w] = smd; }
      }
    }
    __syncthreads();
    if (t < 16) {
      float se = psum[t][0] + psum[t][1];
      float sem = psem[t][0] + psem[t][1];
      float smd = asmd[t][0] + asmd[t][1];
      md_rows[(size_t)bh * A + (r0 + t - V)] = smd / (sem + 1e-13f * se);
    }
    __syncthreads();
  }

  // ---- main softmax sums ----
#pragma unroll
  for (int r = 0; r < 4; ++r) {
    const int lrow = g * 4 + r;
    const float mx = mxA[lrow];
    const float mr = mrwA[lrow];
    float se = 0.f, sem = 0.f;
#pragma unroll
    for (int tn = 0; tn < 12; ++tn) {
      float e = __expf(acc[tn][r] - mx);
      acc[tn][r] = e;
      se += e; sem += e * (mr * mcr[tn]);
    }
#pragma unroll
    for (int o = 1; o < 16; o <<= 1) {
      se += __shfl_xor(se, o, 16);
      sem += __shfl_xor(sem, o, 16);
    }
    if (l15 == 0) { psum[lrow][w] = se; psem[lrow][w] = sem; }
  }
  __syncthreads();
  if (t < 16) {
    float se = psum[t][0] + psum[t][1] + psum[t][2] + psum[t][3];
    float sem = psem[t][0] + psem[t][1] + psem[t][2] + psem[t][3];
    rdA[t] = 1.f / (sem + 1e-13f * se);
  }
  __syncthreads();

  // ---- p writeout + swizzled bf16 P ----
#pragma unroll
  for (int r = 0; r < 4; ++r) {
    const int lrow = g * 4 + r;
    const int row = r0 + lrow;
    const float rden = rdA[lrow];
    const float mr = mrwA[lrow];
    float* prow = &att_map[((size_t)bh * S + row) * S];
    const int swz = (lrow & 7) << 4;
#pragma unroll
    for (int tn = 0; tn < 12; ++tn) {
      const int col = w * 192 + tn * 16 + l15;
      float p = acc[tn][r] * (mr * mcr[tn]) * rden;
      __builtin_nontemporal_store(p, &prow[col]);
      Ps[lrow][col ^ swz] = f2bf(p);
    }
  }
  __syncthreads();

  // ---- PV: ctx(16x64) = P(16x768) @ V(768x64); wave w owns d block [w*16, w*16+16) ----
  {
    const int aswz = (l15 & 7) << 4;
    f32x4 pacc = {};
    const unsigned short* vcol = &vhT[((size_t)bh * D + w * 16 + l15) * S];
#pragma unroll 8
    for (int kk = 0; kk < 24; ++kk) {
      short8 a = *(short8*)&Ps[l15][(kk * 32 + g * 8) ^ aswz];
      short8 bv = *(const short8*)&vcol[kk * 32 + g * 8];
      pacc = mfma16(a, bv, pacc);
    }
#pragma unroll
    for (int r = 0; r < 4; ++r) {
      const int row = r0 + g * 4 + r;
      ctx[((size_t)bh * S + row) * D + w * 16 + l15] = f2bf(pacc[r]);
    }
  }
}

// ---------------- out projection (+ fused md finalize) ----------------
// 1D grid 776: id<768 -> GEMM tile (chunked-XCD swizzle); id>=768 -> md for b=id-768
__global__ __launch_bounds__(256) void gemm_out(
    const unsigned short* __restrict__ Xb, const unsigned short* __restrict__ WT,
    const float* __restrict__ bias, float* __restrict__ Yf,
    const float* __restrict__ md_rows, const float* __restrict__ va_a_mask,
    float* __restrict__ md_out)
{
  const int t = threadIdx.x;
  if (blockIdx.x >= 768) {
    __shared__ float red0[256];
    __shared__ float red1[256];
    const int b = blockIdx.x - 768;
    float s1 = 0.f, s2 = 0.f;
    for (int u = t; u < H * A; u += 256) s1 += md_rows[(size_t)b * H * A + u];
    for (int u = t; u < A; u += 256) s2 += va_a_mask[(size_t)b * A + u];
    red0[t] = s1; red1[t] = s2;
    __syncthreads();
    for (int o = 128; o > 0; o >>= 1) {
      if (t < o) { red0[t] += red0[t + o]; red1[t] += red1[t + o]; }
      __syncthreads();
    }
    const float val = red0[0] / ((float)H * red1[0]);
    for (int u = t; u < A; u += 256) md_out[(size_t)b * A + u] = val;
    return;
  }
  __shared__ unsigned short Bh[64][40];
  const int lin = ((blockIdx.x & 7) * 96) + (blockIdx.x >> 3);
  const int n0 = (lin & 7) * 64;
  const int m0 = (lin >> 3) * 64;
  const int w = t >> 6, lane = t & 63;
  const int l15 = lane & 15, g = lane >> 4;
  const int bb = m0 / S;
  f32x4 acc[4] = {};
  const int srow = t >> 2, skq = (t & 3) * 8;
  for (int k0 = 0; k0 < 512; k0 += 32) {
    __syncthreads();
    *(short8*)&Bh[srow][skq] = *(const short8*)&WT[(size_t)(n0 + srow) * 512 + k0 + skq];
    __syncthreads();
    const int s = m0 + w * 16 + l15 - bb * S;
    const int h = k0 >> 6, d = (k0 & 63) + g * 8;
    short8 ah = *(const short8*)&Xb[((size_t)(bb * H + h) * S + s) * D + d];
#pragma unroll
    for (int tn = 0; tn < 4; ++tn) {
      short8 bh_ = *(short8*)&Bh[tn * 16 + l15][g * 8];
      acc[tn] = mfma16(ah, bh_, acc[tn]);
    }
  }
#pragma unroll
  for (int tn = 0; tn < 4; ++tn) {
    const int c = n0 + tn * 16 + l15;
    const float bi = bias[c];
#pragma unroll
    for (int r = 0; r < 4; ++r) {
      const int m = m0 + w * 16 + g * 4 + r;
      Yf[(size_t)m * 512 + c] = acc[tn][r] + bi;
    }
  }
}

extern "C" void kernel_launch(void* const* d_in, const int* in_sizes, int n_in,
                              void* d_out, int out_size, void* d_ws, size_t ws_size,
                              hipStream_t stream) {
  const float* q           = (const float*)d_in[0];
  const float* k           = (const float*)d_in[1];
  const float* v           = (const float*)d_in[2];
  const float* mask        = (const float*)d_in[3];
  const float* depth_value = (const float*)d_in[4];
  const float* va_a_mask   = (const float*)d_in[7];
  const float* mean_depth  = (const float*)d_in[8];
  const float* Wq = (const float*)d_in[9];
  const float* bq = (const float*)d_in[10];
  const float* Wk = (const float*)d_in[11];
  const float* bk = (const float*)d_in[12];
  const float* Wv = (const float*)d_in[13];
  const float* bv = (const float*)d_in[14];
  const float* Wo = (const float*)d_in[15];
  const float* bo = (const float*)d_in[16];

  unsigned short* wsu = (unsigned short*)d_ws;
  unsigned short* qh  = wsu;                 // aliased by ctx after q-frag reads
  unsigned short* kh  = wsu + N_QH;
  unsigned short* vhT = wsu + 2 * N_QH;
  unsigned short* ctx = qh;                  // alias (per-row ownership matches)
  unsigned short* wt  = wsu + 3 * N_QH;      // 4 weights x 262144 bf16
  float* md_rows = (float*)(wsu + 3 * N_QH + 4 * 262144);

  float* out       = (float*)d_out;
  float* att_score = out + (size_t)B * S * HD;
  float* att_map   = att_score + (size_t)B * H * S * S;
  float* md_out    = att_map + (size_t)B * H * S * S;

  prep_w<<<256, 256, 0, stream>>>(Wq, Wk, Wv, Wo, wt);
  qkv_mfma<<<2304, 256, 0, stream>>>(q, k, v, wt, bq, bk, bv, qh, kh, vhT);
  fused_attn<<<3072, 256, 0, stream>>>(qh, kh, vhT, mask, depth_value, mean_depth,
                                       att_score, att_map, ctx, md_rows);
  gemm_out<<<776, 256, 0, stream>>>(ctx, wt + 3 * 262144, bo, out,
                                    md_rows, va_a_mask, md_out);
}